// Round 2
// baseline (658.730 us; speedup 1.0000x reference)
//
#include <hip/hip_runtime.h>
#include <stdint.h>

// Problem dims (fixed)
#define S_LEN 2048
#define DIM   1024
#define NH    16
#define HDIM  64
#define MTOK  4096   // B*S
#define DFF   4096

typedef short bf16x8 __attribute__((ext_vector_type(8)));
typedef float f32x4  __attribute__((ext_vector_type(4)));

__device__ __forceinline__ unsigned short f2bf(float f) {
  unsigned int u = __float_as_uint(f);
  u += 0x7fffu + ((u >> 16) & 1u);          // RNE
  return (unsigned short)(u >> 16);
}

__device__ __forceinline__ float gelu_f(float x) {
  const float c = 0.7978845608028654f;       // sqrt(2/pi)
  float u = c * (x + 0.044715f * x * x * x);
  return 0.5f * x * (1.0f + tanhf(u));
}

__device__ __forceinline__ void gld_lds16(const void* g, void* lds) {
  using gu32p = __attribute__((address_space(1))) unsigned int*;
  using lu32p = __attribute__((address_space(3))) unsigned int*;
  __builtin_amdgcn_global_load_lds((gu32p)g, (lu32p)lds, 16, 0, 0);
}

// ---------------- cast fp32 -> bf16 (vectorized, 8 elems/thread) -------------
__global__ __launch_bounds__(256) void cast_f32_bf16(const float* __restrict__ x,
                                                     unsigned short* __restrict__ xb) {
  const size_t i = (size_t)blockIdx.x * 256 + threadIdx.x;
  const float4 a = ((const float4*)x)[2 * i];
  const float4 b = ((const float4*)x)[2 * i + 1];
  ushort4 p0, p1;
  p0.x = f2bf(a.x); p0.y = f2bf(a.y); p0.z = f2bf(a.z); p0.w = f2bf(a.w);
  p1.x = f2bf(b.x); p1.y = f2bf(b.y); p1.z = f2bf(b.z); p1.w = f2bf(b.w);
  ((ushort4*)xb)[2 * i]     = p0;
  ((ushort4*)xb)[2 * i + 1] = p1;
}

// ------------- transpose+cast: W[K][N] f32 -> Wt[N][K] bf16 ------------------
__global__ __launch_bounds__(256) void tcast_k(const float* __restrict__ W,
                                               unsigned short* __restrict__ Wt,
                                               int K, int N) {
  __shared__ float tile[32][33];
  const int tx = threadIdx.x & 31, ty = threadIdx.x >> 5;
  const int n0 = blockIdx.x * 32, k0 = blockIdx.y * 32;
#pragma unroll
  for (int i = 0; i < 4; i++)
    tile[ty + 8 * i][tx] = W[(size_t)(k0 + ty + 8 * i) * N + n0 + tx];
  __syncthreads();
#pragma unroll
  for (int i = 0; i < 4; i++)
    Wt[(size_t)(n0 + ty + 8 * i) * K + k0 + tx] = f2bf(tile[tx][ty + 8 * i]);
}

// ------------- transpose v[4096][1024] -> vT[(b,h,d)][s] bf16 ----------------
__global__ __launch_bounds__(256) void vtrans_k(const unsigned short* __restrict__ v,
                                                unsigned short* __restrict__ vT) {
  __shared__ unsigned short tile[64][65];
  const int bh = blockIdx.y, b = bh >> 4, h = bh & 15;
  const int s0 = blockIdx.x * 64;
  const int t = threadIdx.x;
#pragma unroll
  for (int i = 0; i < 16; i++) {
    int idx = i * 256 + t, r = idx >> 6, c = idx & 63;
    tile[r][c] = v[(size_t)(b * S_LEN + s0 + r) * DIM + h * HDIM + c];
  }
  __syncthreads();
#pragma unroll
  for (int i = 0; i < 16; i++) {
    int idx = i * 256 + t, d = idx >> 6, s = idx & 63;
    vT[(size_t)(bh * HDIM + d) * S_LEN + s0 + s] = tile[s][d];
  }
}

// ---------------- GEMM: C = A[M,K](bf16) * Bt[N,K]^T(bf16) + bias ------------
// m97 structure: 128x128 tile, BK=32, 4 waves (2x2 of 64x64), global_load_lds.
// EPI: 0 = bf16 out, 1 = bf16 gelu out, 2 = f32 out + resid add
template <int EPI>
__global__ __launch_bounds__(256) void gemm_bt(const unsigned short* __restrict__ A,
                                               const unsigned short* __restrict__ Bt,
                                               const float* __restrict__ bias,
                                               const float* __restrict__ resid,
                                               void* __restrict__ Cout,
                                               int M, int N, int K) {
  __shared__ alignas(16) short As[128 * 32];
  __shared__ alignas(16) short Bs[128 * 32];
  const int t = threadIdx.x;
  const int w = t >> 6, lane = t & 63;
  const int m0 = blockIdx.y * 128, n0 = blockIdx.x * 128;
  const int wr = (w >> 1) * 64, wc = (w & 1) * 64;
  const int lr = lane & 15, lg = lane >> 4;

  f32x4 acc[4][4] = {};

  const int off0 = w * 2048 + lane * 16;        // byte offset in 8KB tile
  const int r0 = off0 >> 6, c0 = (off0 & 63) >> 1;
  const int off1 = off0 + 1024;
  const int r1 = off1 >> 6, c1 = (off1 & 63) >> 1;

  const unsigned short* Ag0 = A + (size_t)(m0 + r0) * K + c0;
  const unsigned short* Ag1 = A + (size_t)(m0 + r1) * K + c1;
  const unsigned short* Bg0 = Bt + (size_t)(n0 + r0) * K + c0;
  const unsigned short* Bg1 = Bt + (size_t)(n0 + r1) * K + c1;
  char* AsB = (char*)As;
  char* BsB = (char*)Bs;

  for (int k0 = 0; k0 < K; k0 += 32) {
    gld_lds16(Ag0 + k0, AsB + w * 2048);
    gld_lds16(Ag1 + k0, AsB + w * 2048 + 1024);
    gld_lds16(Bg0 + k0, BsB + w * 2048);
    gld_lds16(Bg1 + k0, BsB + w * 2048 + 1024);
    __syncthreads();
    bf16x8 af[4], bfr[4];
#pragma unroll
    for (int i = 0; i < 4; i++) {
      af[i]  = *reinterpret_cast<const bf16x8*>(As + (wr + i * 16 + lr) * 32 + lg * 8);
      bfr[i] = *reinterpret_cast<const bf16x8*>(Bs + (wc + i * 16 + lr) * 32 + lg * 8);
    }
#pragma unroll
    for (int mi = 0; mi < 4; mi++)
#pragma unroll
      for (int ni = 0; ni < 4; ni++)
        acc[mi][ni] = __builtin_amdgcn_mfma_f32_16x16x32_bf16(af[mi], bfr[ni],
                                                              acc[mi][ni], 0, 0, 0);
    __syncthreads();
  }

  // epilogue: D layout col = lane&15, row = (lane>>4)*4 + j
  const int colb = n0 + wc + lr;
  const int rowb = m0 + wr + lg * 4;
#pragma unroll
  for (int ni = 0; ni < 4; ni++) {
    const int col = colb + ni * 16;
    const float bv = bias[col];
#pragma unroll
    for (int mi = 0; mi < 4; mi++) {
#pragma unroll
      for (int j = 0; j < 4; j++) {
        const int row = rowb + mi * 16 + j;
        const size_t idx = (size_t)row * N + col;
        float v = acc[mi][ni][j] + bv;
        if constexpr (EPI == 0) {
          ((unsigned short*)Cout)[idx] = f2bf(v);
        } else if constexpr (EPI == 1) {
          ((unsigned short*)Cout)[idx] = f2bf(gelu_f(v));
        } else {
          ((float*)Cout)[idx] = v + resid[idx];
        }
      }
    }
  }
}

// ---------------- causal flash attention ------------------------------------
// block = 4 waves; wave w handles 16 q-rows (q0 = bx*64 + w*16). No block
// barriers (divergent causal trip counts); per-wave LDS scratch for P^T.
__global__ __launch_bounds__(256) void attn_k(const unsigned short* __restrict__ q,
                                              const unsigned short* __restrict__ k,
                                              const unsigned short* __restrict__ vT,
                                              unsigned short* __restrict__ y) {
  __shared__ alignas(16) short pshm[4][16][32];
  const int t = threadIdx.x, w = t >> 6, lane = t & 63;
  const int lr = lane & 15, lg = lane >> 4;
  const int bh = blockIdx.y, bb = bh >> 4, hh = bh & 15;
  const int q0 = blockIdx.x * 64 + w * 16;

  const size_t qoff = (size_t)(bb * S_LEN + q0 + lr) * DIM + hh * HDIM;
  const bf16x8 qf0 = *reinterpret_cast<const bf16x8*>(q + qoff + lg * 8);
  const bf16x8 qf1 = *reinterpret_cast<const bf16x8*>(q + qoff + 32 + lg * 8);

  float m[4] = {-1e30f, -1e30f, -1e30f, -1e30f};
  float l[4] = {0.f, 0.f, 0.f, 0.f};
  f32x4 acc[4] = {};

  const int kend = q0 + 16;        // causal limit for this wave (exclusive)
  const int qrow = q0 + lg * 4;    // + j

  for (int t0 = 0; t0 < kend; t0 += 32) {
    f32x4 sc[2];
#pragma unroll
    for (int half = 0; half < 2; half++) {
      const int kc = t0 + half * 16 + lr;
      const size_t koff = (size_t)(bb * S_LEN + kc) * DIM + hh * HDIM;
      const bf16x8 kf0 = *reinterpret_cast<const bf16x8*>(k + koff + lg * 8);
      const bf16x8 kf1 = *reinterpret_cast<const bf16x8*>(k + koff + 32 + lg * 8);
      f32x4 s = {};
      s = __builtin_amdgcn_mfma_f32_16x16x32_bf16(qf0, kf0, s, 0, 0, 0);
      s = __builtin_amdgcn_mfma_f32_16x16x32_bf16(qf1, kf1, s, 0, 0, 0);
#pragma unroll
      for (int j = 0; j < 4; j++) {
        float v = s[j] * 0.125f;                       // 1/sqrt(64)
        sc[half][j] = (kc > qrow + j) ? -1e30f : v;    // causal mask
      }
    }
    // row-max over 32 cols (16-lane group holds one 16-col slice per j)
    float mb[4];
#pragma unroll
    for (int j = 0; j < 4; j++) mb[j] = fmaxf(sc[0][j], sc[1][j]);
#pragma unroll
    for (int d = 1; d < 16; d <<= 1)
#pragma unroll
      for (int j = 0; j < 4; j++) mb[j] = fmaxf(mb[j], __shfl_xor(mb[j], d));

    float ps[4];
#pragma unroll
    for (int j = 0; j < 4; j++) {
      const float mn = fmaxf(m[j], mb[j]);
      const float rs = __expf(m[j] - mn);
      m[j] = mn;
      const float p0 = __expf(sc[0][j] - mn);
      const float p1 = __expf(sc[1][j] - mn);
      sc[0][j] = p0; sc[1][j] = p1;
      ps[j] = p0 + p1;
      l[j] *= rs;
#pragma unroll
      for (int ni = 0; ni < 4; ni++) acc[ni][j] *= rs;
    }
#pragma unroll
    for (int d = 1; d < 16; d <<= 1)
#pragma unroll
      for (int j = 0; j < 4; j++) ps[j] += __shfl_xor(ps[j], d);
#pragma unroll
    for (int j = 0; j < 4; j++) l[j] += ps[j];

    // P (D-layout) -> LDS -> A-layout fragment (per-wave scratch, no barrier)
#pragma unroll
    for (int j = 0; j < 4; j++) {
      pshm[w][lg * 4 + j][lr]      = (short)f2bf(sc[0][j]);
      pshm[w][lg * 4 + j][16 + lr] = (short)f2bf(sc[1][j]);
    }
    asm volatile("" ::: "memory");
    const bf16x8 pf = *reinterpret_cast<const bf16x8*>(&pshm[w][lr][lg * 8]);
    asm volatile("" ::: "memory");

#pragma unroll
    for (int ni = 0; ni < 4; ni++) {
      const bf16x8 vf = *reinterpret_cast<const bf16x8*>(
          vT + (size_t)(bh * HDIM + ni * 16 + lr) * S_LEN + t0 + lg * 8);
      acc[ni] = __builtin_amdgcn_mfma_f32_16x16x32_bf16(pf, vf, acc[ni], 0, 0, 0);
    }
  }

#pragma unroll
  for (int ni = 0; ni < 4; ni++)
#pragma unroll
    for (int j = 0; j < 4; j++) {
      const int row = qrow + j;
      y[(size_t)(bb * S_LEN + row) * DIM + hh * HDIM + ni * 16 + lr] =
          f2bf(acc[ni][j] / l[j]);
    }
}

// ---------------- LayerNorm (row = 1024), OUTBF: 1 -> bf16, 0 -> f32 ---------
template <int OUTBF>
__global__ __launch_bounds__(256) void ln_k(const float* __restrict__ X,
                                            const float* __restrict__ g,
                                            const float* __restrict__ be,
                                            void* __restrict__ out) {
  const int row = blockIdx.x, t = threadIdx.x;
  const float4 v = ((const float4*)(X + (size_t)row * DIM))[t];
  float s  = v.x + v.y + v.z + v.w;
  float s2 = v.x * v.x + v.y * v.y + v.z * v.z + v.w * v.w;
#pragma unroll
  for (int o = 32; o >= 1; o >>= 1) {
    s  += __shfl_down(s, o);
    s2 += __shfl_down(s2, o);
  }
  __shared__ float red[8];
  if ((t & 63) == 0) { red[t >> 6] = s; red[4 + (t >> 6)] = s2; }
  __syncthreads();
  s  = red[0] + red[1] + red[2] + red[3];
  s2 = red[4] + red[5] + red[6] + red[7];
  const float mu  = s * (1.0f / DIM);
  const float var = s2 * (1.0f / DIM) - mu * mu;
  const float r   = rsqrtf(var + 1e-5f);
  const float4 gv = ((const float4*)g)[t];
  const float4 bv = ((const float4*)be)[t];
  const float o0 = (v.x - mu) * r * gv.x + bv.x;
  const float o1 = (v.y - mu) * r * gv.y + bv.y;
  const float o2 = (v.z - mu) * r * gv.z + bv.z;
  const float o3 = (v.w - mu) * r * gv.w + bv.w;
  if constexpr (OUTBF) {
    ushort4 p; p.x = f2bf(o0); p.y = f2bf(o1); p.z = f2bf(o2); p.w = f2bf(o3);
    ((ushort4*)out)[(size_t)row * 256 + t] = p;
  } else {
    float4 p; p.x = o0; p.y = o1; p.z = o2; p.w = o3;
    ((float4*)out)[(size_t)row * 256 + t] = p;
  }
}

// ---------------------------------------------------------------------------
extern "C" void kernel_launch(void* const* d_in, const int* in_sizes, int n_in,
                              void* d_out, int out_size, void* d_ws, size_t ws_size,
                              hipStream_t stream) {
  const float* x   = (const float*)d_in[0];
  const float* Wq  = (const float*)d_in[1];
  const float* bq  = (const float*)d_in[2];
  const float* Wk  = (const float*)d_in[3];
  const float* bk  = (const float*)d_in[4];
  const float* Wv  = (const float*)d_in[5];
  const float* bv  = (const float*)d_in[6];
  const float* Wp  = (const float*)d_in[7];
  const float* bp  = (const float*)d_in[8];
  const float* g0  = (const float*)d_in[9];
  const float* be0 = (const float*)d_in[10];
  const float* W1  = (const float*)d_in[11];
  const float* b1  = (const float*)d_in[12];
  const float* W2  = (const float*)d_in[13];
  const float* b2  = (const float*)d_in[14];
  const float* g1  = (const float*)d_in[15];
  const float* be1 = (const float*)d_in[16];

  char* ws = (char*)d_ws;
  const size_t MB = 1ull << 20;
  unsigned short* xb  = (unsigned short*)(ws + 0 * MB);   //  8 MB
  unsigned short* qb  = (unsigned short*)(ws + 8 * MB);   //  8 MB
  unsigned short* kb  = (unsigned short*)(ws + 16 * MB);  //  8 MB
  unsigned short* vb  = (unsigned short*)(ws + 24 * MB);  //  8 MB
  unsigned short* yb  = (unsigned short*)(ws + 32 * MB);  //  8 MB
  unsigned short* vT  = (unsigned short*)(ws + 40 * MB);  //  8 MB
  unsigned short* h1  = (unsigned short*)(ws + 16 * MB);  // 32 MB alias kb..vT (dead by then)
  float*          x2  = (float*)(ws + 0 * MB);            // 16 MB alias xb+qb (dead by then)
  float*          x1  = (float*)(ws + 48 * MB);           // 16 MB
  unsigned short* hb  = (unsigned short*)(ws + 64 * MB);  //  8 MB
  unsigned short* WqT = (unsigned short*)(ws + 72 * MB);  //  2 MB
  unsigned short* WkT = (unsigned short*)(ws + 74 * MB);  //  2 MB
  unsigned short* WvT = (unsigned short*)(ws + 76 * MB);  //  2 MB
  unsigned short* WpT = (unsigned short*)(ws + 78 * MB);  //  2 MB
  unsigned short* W1T = (unsigned short*)(ws + 80 * MB);  //  8 MB
  unsigned short* W2T = (unsigned short*)(ws + 88 * MB);  //  8 MB -> 96 MB total

  // 1) casts / transposes
  cast_f32_bf16<<<2048, 256, 0, stream>>>(x, xb);
  tcast_k<<<dim3(32, 32), 256, 0, stream>>>(Wq, WqT, 1024, 1024);
  tcast_k<<<dim3(32, 32), 256, 0, stream>>>(Wk, WkT, 1024, 1024);
  tcast_k<<<dim3(32, 32), 256, 0, stream>>>(Wv, WvT, 1024, 1024);
  tcast_k<<<dim3(32, 32), 256, 0, stream>>>(Wp, WpT, 1024, 1024);
  tcast_k<<<dim3(128, 32), 256, 0, stream>>>(W1, W1T, 1024, 4096);
  tcast_k<<<dim3(32, 128), 256, 0, stream>>>(W2, W2T, 4096, 1024);

  // 2) QKV projections
  gemm_bt<0><<<dim3(8, 32), 256, 0, stream>>>(xb, WqT, bq, nullptr, qb, MTOK, DIM, DIM);
  gemm_bt<0><<<dim3(8, 32), 256, 0, stream>>>(xb, WkT, bk, nullptr, kb, MTOK, DIM, DIM);
  gemm_bt<0><<<dim3(8, 32), 256, 0, stream>>>(xb, WvT, bv, nullptr, vb, MTOK, DIM, DIM);

  // 3) attention
  vtrans_k<<<dim3(32, 32), 256, 0, stream>>>(vb, vT);
  attn_k<<<dim3(32, 32), 256, 0, stream>>>(qb, kb, vT, yb);

  // 4) out-proj + residual (fp32), LN1 -> bf16
  gemm_bt<2><<<dim3(8, 32), 256, 0, stream>>>(yb, WpT, bp, x, x1, MTOK, DIM, DIM);
  ln_k<1><<<4096, 256, 0, stream>>>(x1, g0, be0, hb);

  // 5) MLP: gelu(h@W1+b1) -> h1 ; h1@W2+b2 + x1 -> x2 ; LN2 -> out (f32)
  gemm_bt<1><<<dim3(32, 32), 256, 0, stream>>>(hb, W1T, b1, nullptr, h1, MTOK, DFF, DIM);
  gemm_bt<2><<<dim3(8, 32), 256, 0, stream>>>(h1, W2T, b2, x1, x2, MTOK, DIM, DFF);
  ln_k<0><<<4096, 256, 0, stream>>>(x2, g1, be1, d_out);
}

// Round 3
// 531.501 us; speedup vs baseline: 1.2394x; 1.2394x over previous
//
#include <hip/hip_runtime.h>
#include <stdint.h>

// Problem dims (fixed)
#define S_LEN 2048
#define DIM   1024
#define NH    16
#define HDIM  64
#define MTOK  4096   // B*S
#define DFF   4096

#define QS 0.18033688011112042f   // 0.125 * log2(e): attn uses exp2

typedef short bf16x8 __attribute__((ext_vector_type(8)));
typedef float f32x4  __attribute__((ext_vector_type(4)));
typedef float f32x16 __attribute__((ext_vector_type(16)));
typedef unsigned int u32x4 __attribute__((ext_vector_type(4)));

__device__ __forceinline__ unsigned short f2bf(float f) {
  unsigned int u = __float_as_uint(f);
  u += 0x7fffu + ((u >> 16) & 1u);          // RNE
  return (unsigned short)(u >> 16);
}

__device__ __forceinline__ unsigned cvtpk(float a, float b) {
  unsigned r;
  asm("v_cvt_pk_bf16_f32 %0, %1, %2" : "=v"(r) : "v"(a), "v"(b));
  return r;
}

__device__ __forceinline__ float gelu_f(float x) {
  const float c = 0.7978845608028654f;       // sqrt(2/pi)
  float u = c * (x + 0.044715f * x * x * x);
  return 0.5f * x * (1.0f + tanhf(u));
}

__device__ __forceinline__ void gld_lds16(const void* g, void* lds) {
  using gu32p = __attribute__((address_space(1))) unsigned int*;
  using lu32p = __attribute__((address_space(3))) unsigned int*;
  __builtin_amdgcn_global_load_lds((gu32p)g, (lu32p)lds, 16, 0, 0);
}

// ---------------- cast fp32 -> bf16 (vectorized, 8 elems/thread) -------------
__global__ __launch_bounds__(256) void cast_f32_bf16(const float* __restrict__ x,
                                                     unsigned short* __restrict__ xb) {
  const size_t i = (size_t)blockIdx.x * 256 + threadIdx.x;
  const float4 a = ((const float4*)x)[2 * i];
  const float4 b = ((const float4*)x)[2 * i + 1];
  ushort4 p0, p1;
  p0.x = f2bf(a.x); p0.y = f2bf(a.y); p0.z = f2bf(a.z); p0.w = f2bf(a.w);
  p1.x = f2bf(b.x); p1.y = f2bf(b.y); p1.z = f2bf(b.z); p1.w = f2bf(b.w);
  ((ushort4*)xb)[2 * i]     = p0;
  ((ushort4*)xb)[2 * i + 1] = p1;
}

// ------------- transpose+cast+scale: W[K][N] f32 -> Wt[N][K] bf16 ------------
__global__ __launch_bounds__(256) void tcast_k(const float* __restrict__ W,
                                               unsigned short* __restrict__ Wt,
                                               int K, int N, float scale) {
  __shared__ float tile[32][33];
  const int tx = threadIdx.x & 31, ty = threadIdx.x >> 5;
  const int n0 = blockIdx.x * 32, k0 = blockIdx.y * 32;
#pragma unroll
  for (int i = 0; i < 4; i++)
    tile[ty + 8 * i][tx] = W[(size_t)(k0 + ty + 8 * i) * N + n0 + tx];
  __syncthreads();
#pragma unroll
  for (int i = 0; i < 4; i++)
    Wt[(size_t)(n0 + ty + 8 * i) * K + k0 + tx] = f2bf(tile[tx][ty + 8 * i] * scale);
}

// ------------- concat (+scale q) biases into bqkv[3072] ----------------------
__global__ __launch_bounds__(256) void bcat_k(const float* __restrict__ bq,
                                              const float* __restrict__ bk,
                                              const float* __restrict__ bv,
                                              float* __restrict__ bqkv) {
  const int t = blockIdx.x * 256 + threadIdx.x;
  float v;
  if (t < 1024)      v = bq[t] * QS;
  else if (t < 2048) v = bk[t - 1024];
  else               v = bv[t - 2048];
  bqkv[t] = v;
}

// ------------- transpose V (inside qkv, stride 3072) -> vT[(b,h,d)][s] -------
__global__ __launch_bounds__(256) void vtrans_k(const unsigned short* __restrict__ qkv,
                                                unsigned short* __restrict__ vT) {
  __shared__ unsigned short tile[64][65];
  const int bh = blockIdx.y, b = bh >> 4, h = bh & 15;
  const int s0 = blockIdx.x * 64;
  const int t = threadIdx.x;
#pragma unroll
  for (int i = 0; i < 16; i++) {
    int idx = i * 256 + t, r = idx >> 6, c = idx & 63;
    tile[r][c] = qkv[(size_t)(b * S_LEN + s0 + r) * 3072 + 2048 + h * HDIM + c];
  }
  __syncthreads();
#pragma unroll
  for (int i = 0; i < 16; i++) {
    int idx = i * 256 + t, d = idx >> 6, s = idx & 63;
    vT[(size_t)(bh * HDIM + d) * S_LEN + s0 + s] = tile[s][d];
  }
}

// ---------------- GEMM: C = A[M,K](bf16) * Bt[N,K]^T(bf16) + bias ------------
// EPI: 0 = bf16 out, 1 = bf16 gelu out, 2 = f32 out + resid add
template <int EPI>
__global__ __launch_bounds__(256) void gemm_bt(const unsigned short* __restrict__ A,
                                               const unsigned short* __restrict__ Bt,
                                               const float* __restrict__ bias,
                                               const float* __restrict__ resid,
                                               void* __restrict__ Cout,
                                               int M, int N, int K) {
  __shared__ alignas(16) short As[128 * 32];
  __shared__ alignas(16) short Bs[128 * 32];
  const int t = threadIdx.x;
  const int w = t >> 6, lane = t & 63;
  const int m0 = blockIdx.y * 128, n0 = blockIdx.x * 128;
  const int wr = (w >> 1) * 64, wc = (w & 1) * 64;
  const int lr = lane & 15, lg = lane >> 4;

  f32x4 acc[4][4] = {};

  const int off0 = w * 2048 + lane * 16;        // byte offset in 8KB tile
  const int r0 = off0 >> 6, c0 = (off0 & 63) >> 1;
  const int off1 = off0 + 1024;
  const int r1 = off1 >> 6, c1 = (off1 & 63) >> 1;

  const unsigned short* Ag0 = A + (size_t)(m0 + r0) * K + c0;
  const unsigned short* Ag1 = A + (size_t)(m0 + r1) * K + c1;
  const unsigned short* Bg0 = Bt + (size_t)(n0 + r0) * K + c0;
  const unsigned short* Bg1 = Bt + (size_t)(n0 + r1) * K + c1;
  char* AsB = (char*)As;
  char* BsB = (char*)Bs;

  for (int k0 = 0; k0 < K; k0 += 32) {
    gld_lds16(Ag0 + k0, AsB + w * 2048);
    gld_lds16(Ag1 + k0, AsB + w * 2048 + 1024);
    gld_lds16(Bg0 + k0, BsB + w * 2048);
    gld_lds16(Bg1 + k0, BsB + w * 2048 + 1024);
    __syncthreads();
    bf16x8 af[4], bfr[4];
#pragma unroll
    for (int i = 0; i < 4; i++) {
      af[i]  = *reinterpret_cast<const bf16x8*>(As + (wr + i * 16 + lr) * 32 + lg * 8);
      bfr[i] = *reinterpret_cast<const bf16x8*>(Bs + (wc + i * 16 + lr) * 32 + lg * 8);
    }
#pragma unroll
    for (int mi = 0; mi < 4; mi++)
#pragma unroll
      for (int ni = 0; ni < 4; ni++)
        acc[mi][ni] = __builtin_amdgcn_mfma_f32_16x16x32_bf16(af[mi], bfr[ni],
                                                              acc[mi][ni], 0, 0, 0);
    __syncthreads();
  }

  // epilogue: D layout col = lane&15, row = (lane>>4)*4 + j
  const int colb = n0 + wc + lr;
  const int rowb = m0 + wr + lg * 4;
#pragma unroll
  for (int ni = 0; ni < 4; ni++) {
    const int col = colb + ni * 16;
    const float bv = bias[col];
#pragma unroll
    for (int mi = 0; mi < 4; mi++) {
#pragma unroll
      for (int j = 0; j < 4; j++) {
        const int row = rowb + mi * 16 + j;
        const size_t idx = (size_t)row * N + col;
        float v = acc[mi][ni][j] + bv;
        if constexpr (EPI == 0) {
          ((unsigned short*)Cout)[idx] = f2bf(v);
        } else if constexpr (EPI == 1) {
          ((unsigned short*)Cout)[idx] = f2bf(gelu_f(v));
        } else {
          ((float*)Cout)[idx] = v + resid[idx];
        }
      }
    }
  }
}

// ---------------- causal flash attention, 32x32 MFMA, swapped QK^T -----------
// 4 waves/block: wave pair (2t, 2t+1) handles one 32-row q-tile, split over
// key-tile parity. In-register softmax (q = lane&31), defer-max, exp2 logits
// (Q pre-scaled by 0.125*log2e). LDS used only for end-of-kernel K-half merge
// and the output transpose.
__global__ __launch_bounds__(256, 3) void attn32_k(const unsigned short* __restrict__ qkv,
                                                   const unsigned short* __restrict__ vT,
                                                   unsigned short* __restrict__ y) {
  __shared__ float smem[4][64][33];
  __shared__ float msh[4][64], lsh[4][64];

  const int t = threadIdx.x, w = t >> 6, lane = t & 63;
  const int ql = lane & 31, hi = lane >> 5;
  const int bh = blockIdx.y, bb = bh >> 4, hh = bh & 15;
  const int qt = 63 - (blockIdx.x * 2 + (w >> 1));   // heavy tiles first
  const int half = w & 1;
  const int q0 = qt * 32;

  // Q fragments (B-operand): Q[q0+ql][hh*64 + ks*16 + hi*8 + i]
  const unsigned short* qp = qkv + (size_t)(bb * S_LEN + q0 + ql) * 3072 + hh * HDIM + hi * 8;
  const bf16x8 qf0 = *(const bf16x8*)(qp);
  const bf16x8 qf1 = *(const bf16x8*)(qp + 16);
  const bf16x8 qf2 = *(const bf16x8*)(qp + 32);
  const bf16x8 qf3 = *(const bf16x8*)(qp + 48);

  const unsigned short* kbp = qkv + (size_t)(bb * S_LEN) * 3072 + 1024 + hh * HDIM + hi * 8;
  const unsigned short* vbp = vT + (size_t)(bh * HDIM + ql) * (size_t)S_LEN + hi * 8;

  f32x16 acc0 = {}, acc1 = {};
  float m = -1e30f, l = 0.f;

  for (int t0 = half * 32; t0 <= q0; t0 += 64) {
    // S^T[key][q] = K · Q^T   (keys = rows)
    const unsigned short* kp = kbp + (size_t)(t0 + ql) * 3072;
    const bf16x8 kf0 = *(const bf16x8*)(kp);
    const bf16x8 kf1 = *(const bf16x8*)(kp + 16);
    const bf16x8 kf2 = *(const bf16x8*)(kp + 32);
    const bf16x8 kf3 = *(const bf16x8*)(kp + 48);
    f32x16 st = {};
    st = __builtin_amdgcn_mfma_f32_32x32x16_bf16(kf0, qf0, st, 0, 0, 0);
    st = __builtin_amdgcn_mfma_f32_32x32x16_bf16(kf1, qf1, st, 0, 0, 0);
    st = __builtin_amdgcn_mfma_f32_32x32x16_bf16(kf2, qf2, st, 0, 0, 0);
    st = __builtin_amdgcn_mfma_f32_32x32x16_bf16(kf3, qf3, st, 0, 0, 0);

    if (t0 == q0) {                         // diagonal tile: causal mask
#pragma unroll
      for (int r = 0; r < 16; r++) {
        const int key = (r & 3) + 8 * (r >> 2) + 4 * hi;
        if (key > ql) st[r] = -1e30f;
      }
    }
    float pm = st[0];
#pragma unroll
    for (int r = 1; r < 16; r++) pm = fmaxf(pm, st[r]);
    pm = fmaxf(pm, __shfl_xor(pm, 32));
    if (!__all(pm - m <= 8.f)) {            // defer-max (T13)
      const float mn = fmaxf(m, pm);
      const float rs = exp2f(m - mn);
      l *= rs;
#pragma unroll
      for (int r = 0; r < 16; r++) { acc0[r] *= rs; acc1[r] *= rs; }
      m = mn;
    }
    float p[16];
    float sum = 0.f;
#pragma unroll
    for (int r = 0; r < 16; r++) { p[r] = exp2f(st[r] - m); sum += p[r]; }
    sum += __shfl_xor(sum, 32);
    l += sum;

    const unsigned short* vp = vbp + t0;
    {   // P^T B-frag, keys 0..15 of tile
      const unsigned c0 = cvtpk(p[0], p[1]), c1 = cvtpk(p[2], p[3]);
      const unsigned c2 = cvtpk(p[4], p[5]), c3 = cvtpk(p[6], p[7]);
      const unsigned x0 = __shfl_xor(c0, 32), x1 = __shfl_xor(c1, 32);
      const unsigned x2 = __shfl_xor(c2, 32), x3 = __shfl_xor(c3, 32);
      u32x4 fu;
      fu.x = hi ? x2 : c0; fu.y = hi ? x3 : c1;
      fu.z = hi ? c2 : x0; fu.w = hi ? c3 : x1;
      const bf16x8 pf = __builtin_bit_cast(bf16x8, fu);
      const bf16x8 v0 = *(const bf16x8*)(vp);
      const bf16x8 v1 = *(const bf16x8*)(vp + 32 * S_LEN);
      acc0 = __builtin_amdgcn_mfma_f32_32x32x16_bf16(v0, pf, acc0, 0, 0, 0);
      acc1 = __builtin_amdgcn_mfma_f32_32x32x16_bf16(v1, pf, acc1, 0, 0, 0);
    }
    {   // keys 16..31
      const unsigned c4 = cvtpk(p[8], p[9]),  c5 = cvtpk(p[10], p[11]);
      const unsigned c6 = cvtpk(p[12], p[13]), c7 = cvtpk(p[14], p[15]);
      const unsigned x4 = __shfl_xor(c4, 32), x5 = __shfl_xor(c5, 32);
      const unsigned x6 = __shfl_xor(c6, 32), x7 = __shfl_xor(c7, 32);
      u32x4 fu;
      fu.x = hi ? x6 : c4; fu.y = hi ? x7 : c5;
      fu.z = hi ? c6 : x4; fu.w = hi ? c7 : x5;
      const bf16x8 pf = __builtin_bit_cast(bf16x8, fu);
      const bf16x8 v0 = *(const bf16x8*)(vp + 16);
      const bf16x8 v1 = *(const bf16x8*)(vp + 32 * S_LEN + 16);
      acc0 = __builtin_amdgcn_mfma_f32_32x32x16_bf16(v0, pf, acc0, 0, 0, 0);
      acc1 = __builtin_amdgcn_mfma_f32_32x32x16_bf16(v1, pf, acc1, 0, 0, 0);
    }
  }

  // ---- K-half merge via LDS ----
#pragma unroll
  for (int r = 0; r < 16; r++) {
    smem[w][lane][r]      = acc0[r];
    smem[w][lane][16 + r] = acc1[r];
  }
  msh[w][lane] = m; lsh[w][lane] = l;
  __syncthreads();
  if (half) return;

  const int pw = w ^ 1;
  const float mB = msh[pw][lane], lB = lsh[pw][lane];
  const float mm = fmaxf(m, mB);
  float sA = exp2f(m - mm), sB = exp2f(mB - mm);
  const float linv = 1.f / (l * sA + lB * sB);
  sA *= linv; sB *= linv;

  unsigned* tp = (unsigned*)&smem[w][0][0];       // reuse own slot: [32][34] u32
  const float* pa = &smem[pw][lane][0];
#pragma unroll
  for (int j = 0; j < 8; j++) {
    const int wd = (j & 1) + 4 * (j >> 1) + 2 * hi;
    const float a0 = acc0[2 * j] * sA + pa[2 * j] * sB;
    const float b0 = acc0[2 * j + 1] * sA + pa[2 * j + 1] * sB;
    tp[ql * 34 + wd] = cvtpk(a0, b0);
    const float a1 = acc1[2 * j] * sA + pa[16 + 2 * j] * sB;
    const float b1 = acc1[2 * j + 1] * sA + pa[16 + 2 * j + 1] * sB;
    tp[ql * 34 + 16 + wd] = cvtpk(a1, b1);
  }
  // read rows back (lane -> row ql, half hi) and store coalesced
  unsigned* yu = (unsigned*)y;
  const size_t yrow = (size_t)(bb * S_LEN + q0 + ql) * (DIM / 2) + hh * (HDIM / 2) + hi * 16;
#pragma unroll
  for (int i = 0; i < 8; i++) {
    const uint2 d2 = *(const uint2*)&tp[ql * 34 + hi * 16 + 2 * i];
    *(uint2*)&yu[yrow + 2 * i] = d2;
  }
}

// ---------------- LayerNorm (row = 1024), OUTBF: 1 -> bf16, 0 -> f32 ---------
template <int OUTBF>
__global__ __launch_bounds__(256) void ln_k(const float* __restrict__ X,
                                            const float* __restrict__ g,
                                            const float* __restrict__ be,
                                            void* __restrict__ out) {
  const int row = blockIdx.x, t = threadIdx.x;
  const float4 v = ((const float4*)(X + (size_t)row * DIM))[t];
  float s  = v.x + v.y + v.z + v.w;
  float s2 = v.x * v.x + v.y * v.y + v.z * v.z + v.w * v.w;
#pragma unroll
  for (int o = 32; o >= 1; o >>= 1) {
    s  += __shfl_down(s, o);
    s2 += __shfl_down(s2, o);
  }
  __shared__ float red[8];
  if ((t & 63) == 0) { red[t >> 6] = s; red[4 + (t >> 6)] = s2; }
  __syncthreads();
  s  = red[0] + red[1] + red[2] + red[3];
  s2 = red[4] + red[5] + red[6] + red[7];
  const float mu  = s * (1.0f / DIM);
  const float var = s2 * (1.0f / DIM) - mu * mu;
  const float r   = rsqrtf(var + 1e-5f);
  const float4 gv = ((const float4*)g)[t];
  const float4 bv = ((const float4*)be)[t];
  const float o0 = (v.x - mu) * r * gv.x + bv.x;
  const float o1 = (v.y - mu) * r * gv.y + bv.y;
  const float o2 = (v.z - mu) * r * gv.z + bv.z;
  const float o3 = (v.w - mu) * r * gv.w + bv.w;
  if constexpr (OUTBF) {
    ushort4 p; p.x = f2bf(o0); p.y = f2bf(o1); p.z = f2bf(o2); p.w = f2bf(o3);
    ((ushort4*)out)[(size_t)row * 256 + t] = p;
  } else {
    float4 p; p.x = o0; p.y = o1; p.z = o2; p.w = o3;
    ((float4*)out)[(size_t)row * 256 + t] = p;
  }
}

// ---------------------------------------------------------------------------
extern "C" void kernel_launch(void* const* d_in, const int* in_sizes, int n_in,
                              void* d_out, int out_size, void* d_ws, size_t ws_size,
                              hipStream_t stream) {
  const float* x   = (const float*)d_in[0];
  const float* Wq  = (const float*)d_in[1];
  const float* bq  = (const float*)d_in[2];
  const float* Wk  = (const float*)d_in[3];
  const float* bk  = (const float*)d_in[4];
  const float* Wv  = (const float*)d_in[5];
  const float* bv  = (const float*)d_in[6];
  const float* Wp  = (const float*)d_in[7];
  const float* bp  = (const float*)d_in[8];
  const float* g0  = (const float*)d_in[9];
  const float* be0 = (const float*)d_in[10];
  const float* W1  = (const float*)d_in[11];
  const float* b1  = (const float*)d_in[12];
  const float* W2  = (const float*)d_in[13];
  const float* b2  = (const float*)d_in[14];
  const float* g1  = (const float*)d_in[15];
  const float* be1 = (const float*)d_in[16];

  char* ws = (char*)d_ws;
  const size_t MB = 1ull << 20;
  unsigned short* xb    = (unsigned short*)(ws + 0 * MB);   //  8 MB
  unsigned short* qkvb  = (unsigned short*)(ws + 8 * MB);   // 24 MB [4096][3072]
  unsigned short* vTb   = (unsigned short*)(ws + 32 * MB);  //  8 MB
  unsigned short* yb    = (unsigned short*)(ws + 40 * MB);  //  8 MB
  float*          bqkv  = (float*)(ws + 48 * MB);           // 12 KB (dead before x1 write)
  float*          x1    = (float*)(ws + 48 * MB);           // 16 MB
  unsigned short* hb    = (unsigned short*)(ws + 64 * MB);  //  8 MB
  unsigned short* WqkvT = (unsigned short*)(ws + 72 * MB);  //  6 MB [3072][1024]
  unsigned short* WpT   = (unsigned short*)(ws + 78 * MB);  //  2 MB
  unsigned short* W1T   = (unsigned short*)(ws + 80 * MB);  //  8 MB
  unsigned short* W2T   = (unsigned short*)(ws + 88 * MB);  //  8 MB -> 96 MB
  unsigned short* h1    = (unsigned short*)(ws + 8 * MB);   // 32 MB alias qkvb+vTb (dead)
  float*          x2    = (float*)(ws + 64 * MB);           // 16 MB alias hb+WqkvT+WpT (dead)

  // 1) casts / transposes (Q weights+bias pre-scaled by 0.125*log2e)
  cast_f32_bf16<<<2048, 256, 0, stream>>>(x, xb);
  tcast_k<<<dim3(32, 32), 256, 0, stream>>>(Wq, WqkvT,               1024, 1024, QS);
  tcast_k<<<dim3(32, 32), 256, 0, stream>>>(Wk, WqkvT + 1024 * 1024, 1024, 1024, 1.f);
  tcast_k<<<dim3(32, 32), 256, 0, stream>>>(Wv, WqkvT + 2048 * 1024, 1024, 1024, 1.f);
  tcast_k<<<dim3(32, 32), 256, 0, stream>>>(Wp, WpT, 1024, 1024, 1.f);
  tcast_k<<<dim3(128, 32), 256, 0, stream>>>(W1, W1T, 1024, 4096, 1.f);
  tcast_k<<<dim3(32, 128), 256, 0, stream>>>(W2, W2T, 4096, 1024, 1.f);
  bcat_k<<<12, 256, 0, stream>>>(bq, bk, bv, bqkv);

  // 2) fused QKV projection: [4096][3072]
  gemm_bt<0><<<dim3(24, 32), 256, 0, stream>>>(xb, WqkvT, bqkv, nullptr, qkvb, MTOK, 3072, 1024);

  // 3) attention
  vtrans_k<<<dim3(32, 32), 256, 0, stream>>>(qkvb, vTb);
  attn32_k<<<dim3(32, 32), 256, 0, stream>>>(qkvb, vTb, yb);

  // 4) out-proj + residual (fp32), LN1 -> bf16
  gemm_bt<2><<<dim3(8, 32), 256, 0, stream>>>(yb, WpT, bp, x, x1, MTOK, DIM, DIM);
  ln_k<1><<<4096, 256, 0, stream>>>(x1, g0, be0, hb);

  // 5) MLP: gelu(h@W1+b1) -> h1 ; h1@W2+b2 + x1 -> x2 ; LN2 -> out (f32)
  gemm_bt<1><<<dim3(32, 32), 256, 0, stream>>>(hb, W1T, b1, nullptr, h1, MTOK, DFF, DIM);
  gemm_bt<2><<<dim3(8, 32), 256, 0, stream>>>(h1, W2T, b2, x1, x2, MTOK, DIM, DFF);
  ln_k<0><<<4096, 256, 0, stream>>>(x2, g1, be1, d_out);
}

// Round 4
// 527.062 us; speedup vs baseline: 1.2498x; 1.0084x over previous
//
#include <hip/hip_runtime.h>
#include <stdint.h>

// Problem dims (fixed)
#define S_LEN 2048
#define DIM   1024
#define NH    16
#define HDIM  64
#define MTOK  4096   // B*S
#define DFF   4096

#define QS 0.18033688011112042f   // 0.125 * log2(e): attn uses exp2

typedef short bf16x8 __attribute__((ext_vector_type(8)));
typedef float f32x4  __attribute__((ext_vector_type(4)));
typedef float f32x16 __attribute__((ext_vector_type(16)));
typedef unsigned int u32x4 __attribute__((ext_vector_type(4)));

__device__ __forceinline__ unsigned short f2bf(float f) {
  unsigned int u = __float_as_uint(f);
  u += 0x7fffu + ((u >> 16) & 1u);          // RNE
  return (unsigned short)(u >> 16);
}

__device__ __forceinline__ unsigned cvtpk(float a, float b) {
  unsigned r;
  asm("v_cvt_pk_bf16_f32 %0, %1, %2" : "=v"(r) : "v"(a), "v"(b));
  return r;
}

__device__ __forceinline__ float gelu_f(float x) {
  const float c = 0.7978845608028654f;       // sqrt(2/pi)
  float u = c * (x + 0.044715f * x * x * x);
  return 0.5f * x * (1.0f + tanhf(u));
}

__device__ __forceinline__ void gld_lds16(const void* g, void* lds) {
  using gu32p = __attribute__((address_space(1))) unsigned int*;
  using lu32p = __attribute__((address_space(3))) unsigned int*;
  __builtin_amdgcn_global_load_lds((gu32p)g, (lu32p)lds, 16, 0, 0);
}

// ---------------- cast fp32 -> bf16 (vectorized, 8 elems/thread) -------------
__global__ __launch_bounds__(256) void cast_f32_bf16(const float* __restrict__ x,
                                                     unsigned short* __restrict__ xb) {
  const size_t i = (size_t)blockIdx.x * 256 + threadIdx.x;
  const float4 a = ((const float4*)x)[2 * i];
  const float4 b = ((const float4*)x)[2 * i + 1];
  ushort4 p0, p1;
  p0.x = f2bf(a.x); p0.y = f2bf(a.y); p0.z = f2bf(a.z); p0.w = f2bf(a.w);
  p1.x = f2bf(b.x); p1.y = f2bf(b.y); p1.z = f2bf(b.z); p1.w = f2bf(b.w);
  ((ushort4*)xb)[2 * i]     = p0;
  ((ushort4*)xb)[2 * i + 1] = p1;
}

// ------------- transpose+cast+scale: W[K][N] f32 -> Wt[N][K] bf16 ------------
__global__ __launch_bounds__(256) void tcast_k(const float* __restrict__ W,
                                               unsigned short* __restrict__ Wt,
                                               int K, int N, float scale) {
  __shared__ float tile[32][33];
  const int tx = threadIdx.x & 31, ty = threadIdx.x >> 5;
  const int n0 = blockIdx.x * 32, k0 = blockIdx.y * 32;
#pragma unroll
  for (int i = 0; i < 4; i++)
    tile[ty + 8 * i][tx] = W[(size_t)(k0 + ty + 8 * i) * N + n0 + tx];
  __syncthreads();
#pragma unroll
  for (int i = 0; i < 4; i++)
    Wt[(size_t)(n0 + ty + 8 * i) * K + k0 + tx] = f2bf(tile[tx][ty + 8 * i] * scale);
}

// ------------- concat (+scale q) biases into bqkv[3072] ----------------------
__global__ __launch_bounds__(256) void bcat_k(const float* __restrict__ bq,
                                              const float* __restrict__ bk,
                                              const float* __restrict__ bv,
                                              float* __restrict__ bqkv) {
  const int t = blockIdx.x * 256 + threadIdx.x;
  float v;
  if (t < 1024)      v = bq[t] * QS;
  else if (t < 2048) v = bk[t - 1024];
  else               v = bv[t - 2048];
  bqkv[t] = v;
}

// ------------- transpose V (inside qkv, stride 3072) -> vT[(b,h,d)][s] -------
__global__ __launch_bounds__(256) void vtrans_k(const unsigned short* __restrict__ qkv,
                                                unsigned short* __restrict__ vT) {
  __shared__ unsigned short tile[64][65];
  const int bh = blockIdx.y, b = bh >> 4, h = bh & 15;
  const int s0 = blockIdx.x * 64;
  const int t = threadIdx.x;
#pragma unroll
  for (int i = 0; i < 16; i++) {
    int idx = i * 256 + t, r = idx >> 6, c = idx & 63;
    tile[r][c] = qkv[(size_t)(b * S_LEN + s0 + r) * 3072 + 2048 + h * HDIM + c];
  }
  __syncthreads();
#pragma unroll
  for (int i = 0; i < 16; i++) {
    int idx = i * 256 + t, d = idx >> 6, s = idx & 63;
    vT[(size_t)(bh * HDIM + d) * S_LEN + s0 + s] = tile[s][d];
  }
}

// ---------------- GEMM: C = A[M,K](bf16) * Bt[N,K]^T(bf16) + bias ------------
// EPI: 0 = bf16 out, 1 = bf16 gelu out, 2 = f32 out + resid add
template <int EPI>
__global__ __launch_bounds__(256) void gemm_bt(const unsigned short* __restrict__ A,
                                               const unsigned short* __restrict__ Bt,
                                               const float* __restrict__ bias,
                                               const float* __restrict__ resid,
                                               void* __restrict__ Cout,
                                               int M, int N, int K) {
  __shared__ alignas(16) short As[128 * 32];
  __shared__ alignas(16) short Bs[128 * 32];
  const int t = threadIdx.x;
  const int w = t >> 6, lane = t & 63;
  const int m0 = blockIdx.y * 128, n0 = blockIdx.x * 128;
  const int wr = (w >> 1) * 64, wc = (w & 1) * 64;
  const int lr = lane & 15, lg = lane >> 4;

  f32x4 acc[4][4] = {};

  const int off0 = w * 2048 + lane * 16;        // byte offset in 8KB tile
  const int r0 = off0 >> 6, c0 = (off0 & 63) >> 1;
  const int off1 = off0 + 1024;
  const int r1 = off1 >> 6, c1 = (off1 & 63) >> 1;

  const unsigned short* Ag0 = A + (size_t)(m0 + r0) * K + c0;
  const unsigned short* Ag1 = A + (size_t)(m0 + r1) * K + c1;
  const unsigned short* Bg0 = Bt + (size_t)(n0 + r0) * K + c0;
  const unsigned short* Bg1 = Bt + (size_t)(n0 + r1) * K + c1;
  char* AsB = (char*)As;
  char* BsB = (char*)Bs;

  for (int k0 = 0; k0 < K; k0 += 32) {
    gld_lds16(Ag0 + k0, AsB + w * 2048);
    gld_lds16(Ag1 + k0, AsB + w * 2048 + 1024);
    gld_lds16(Bg0 + k0, BsB + w * 2048);
    gld_lds16(Bg1 + k0, BsB + w * 2048 + 1024);
    __syncthreads();
    bf16x8 af[4], bfr[4];
#pragma unroll
    for (int i = 0; i < 4; i++) {
      af[i]  = *reinterpret_cast<const bf16x8*>(As + (wr + i * 16 + lr) * 32 + lg * 8);
      bfr[i] = *reinterpret_cast<const bf16x8*>(Bs + (wc + i * 16 + lr) * 32 + lg * 8);
    }
#pragma unroll
    for (int mi = 0; mi < 4; mi++)
#pragma unroll
      for (int ni = 0; ni < 4; ni++)
        acc[mi][ni] = __builtin_amdgcn_mfma_f32_16x16x32_bf16(af[mi], bfr[ni],
                                                              acc[mi][ni], 0, 0, 0);
    __syncthreads();
  }

  // epilogue: D layout col = lane&15, row = (lane>>4)*4 + j
  const int colb = n0 + wc + lr;
  const int rowb = m0 + wr + lg * 4;
#pragma unroll
  for (int ni = 0; ni < 4; ni++) {
    const int col = colb + ni * 16;
    const float bv = bias[col];
#pragma unroll
    for (int mi = 0; mi < 4; mi++) {
#pragma unroll
      for (int j = 0; j < 4; j++) {
        const int row = rowb + mi * 16 + j;
        const size_t idx = (size_t)row * N + col;
        float v = acc[mi][ni][j] + bv;
        if constexpr (EPI == 0) {
          ((unsigned short*)Cout)[idx] = f2bf(v);
        } else if constexpr (EPI == 1) {
          ((unsigned short*)Cout)[idx] = f2bf(gelu_f(v));
        } else {
          ((float*)Cout)[idx] = v + resid[idx];
        }
      }
    }
  }
}

// ---------------- causal flash attention, 32x32 MFMA, swapped QK^T -----------
// 4 waves/block: wave pair (2t, 2t+1) handles one 32-row q-tile, split over
// key-tile parity. In-register softmax (q = lane&31), defer-max, exp2 logits
// (Q pre-scaled by 0.125*log2e). Software-pipelined: K prefetched one tile
// ahead (clamped addr on last iter), V-tile loads hoisted to loop top so
// softmax VALU covers their latency. LDS only for K-half merge + O transpose.
__global__ __launch_bounds__(256, 3) void attn32_k(const unsigned short* __restrict__ qkv,
                                                   const unsigned short* __restrict__ vT,
                                                   unsigned short* __restrict__ y) {
  __shared__ float smem[4][64][33];
  __shared__ float msh[4][64], lsh[4][64];

  const int t = threadIdx.x, w = t >> 6, lane = t & 63;
  const int ql = lane & 31, hi = lane >> 5;
  const int bh = blockIdx.y, bb = bh >> 4, hh = bh & 15;
  const int qt = 63 - (blockIdx.x * 2 + (w >> 1));   // heavy tiles first
  const int half = w & 1;
  const int q0 = qt * 32;

  // Q fragments (B-operand): Q[q0+ql][hh*64 + ks*16 + hi*8 + i]
  const unsigned short* qp = qkv + (size_t)(bb * S_LEN + q0 + ql) * 3072 + hh * HDIM + hi * 8;
  const bf16x8 qf0 = *(const bf16x8*)(qp);
  const bf16x8 qf1 = *(const bf16x8*)(qp + 16);
  const bf16x8 qf2 = *(const bf16x8*)(qp + 32);
  const bf16x8 qf3 = *(const bf16x8*)(qp + 48);

  const unsigned short* kbp = qkv + (size_t)(bb * S_LEN) * 3072 + 1024 + hh * HDIM + hi * 8;
  const unsigned short* vbp = vT + (size_t)(bh * HDIM + ql) * (size_t)S_LEN + hi * 8;

  f32x16 acc0 = {}, acc1 = {};
  float m = -1e30f, l = 0.f;

  const int start = half * 32;

  // K prologue load (tile at `start`; rows < S_LEN even when loop is empty)
  const unsigned short* kp0 = kbp + (size_t)(start + ql) * 3072;
  bf16x8 kc0 = *(const bf16x8*)(kp0);
  bf16x8 kc1 = *(const bf16x8*)(kp0 + 16);
  bf16x8 kc2 = *(const bf16x8*)(kp0 + 32);
  bf16x8 kc3 = *(const bf16x8*)(kp0 + 48);

  for (int t0 = start; t0 <= q0; t0 += 64) {
    // V current-tile loads issue first; softmax below covers their latency
    const unsigned short* vp = vbp + t0;
    const bf16x8 vf0 = *(const bf16x8*)(vp);
    const bf16x8 vf1 = *(const bf16x8*)(vp + 32 * S_LEN);
    const bf16x8 vf2 = *(const bf16x8*)(vp + 16);
    const bf16x8 vf3 = *(const bf16x8*)(vp + 32 * S_LEN + 16);

    // S^T[key][q] = K · Q^T   (keys = rows)
    __builtin_amdgcn_s_setprio(1);
    f32x16 st = {};
    st = __builtin_amdgcn_mfma_f32_32x32x16_bf16(kc0, qf0, st, 0, 0, 0);
    st = __builtin_amdgcn_mfma_f32_32x32x16_bf16(kc1, qf1, st, 0, 0, 0);
    st = __builtin_amdgcn_mfma_f32_32x32x16_bf16(kc2, qf2, st, 0, 0, 0);
    st = __builtin_amdgcn_mfma_f32_32x32x16_bf16(kc3, qf3, st, 0, 0, 0);
    __builtin_amdgcn_s_setprio(0);

    // K prefetch for t0+64 (clamped in-bounds on final iteration)
    const int t1 = (t0 + 64 <= q0) ? (t0 + 64) : t0;
    const unsigned short* kpn = kbp + (size_t)(t1 + ql) * 3072;
    const bf16x8 kn0 = *(const bf16x8*)(kpn);
    const bf16x8 kn1 = *(const bf16x8*)(kpn + 16);
    const bf16x8 kn2 = *(const bf16x8*)(kpn + 32);
    const bf16x8 kn3 = *(const bf16x8*)(kpn + 48);

    if (t0 == q0) {                         // diagonal tile: causal mask
#pragma unroll
      for (int r = 0; r < 16; r++) {
        const int key = (r & 3) + 8 * (r >> 2) + 4 * hi;
        if (key > ql) st[r] = -1e30f;
      }
    }
    float pm = st[0];
#pragma unroll
    for (int r = 1; r < 16; r++) pm = fmaxf(pm, st[r]);
    pm = fmaxf(pm, __shfl_xor(pm, 32));
    if (!__all(pm - m <= 8.f)) {            // defer-max (T13)
      const float mn = fmaxf(m, pm);
      const float rs = exp2f(m - mn);
      l *= rs;
#pragma unroll
      for (int r = 0; r < 16; r++) { acc0[r] *= rs; acc1[r] *= rs; }
      m = mn;
    }
    float sum = 0.f;
#pragma unroll
    for (int r = 0; r < 16; r++) { st[r] = exp2f(st[r] - m); sum += st[r]; }
    sum += __shfl_xor(sum, 32);
    l += sum;

    {   // P^T B-frag, keys 0..15 of tile
      const unsigned c0 = cvtpk(st[0], st[1]), c1 = cvtpk(st[2], st[3]);
      const unsigned c2 = cvtpk(st[4], st[5]), c3 = cvtpk(st[6], st[7]);
      const unsigned x0 = __shfl_xor(c0, 32), x1 = __shfl_xor(c1, 32);
      const unsigned x2 = __shfl_xor(c2, 32), x3 = __shfl_xor(c3, 32);
      u32x4 fu;
      fu.x = hi ? x2 : c0; fu.y = hi ? x3 : c1;
      fu.z = hi ? c2 : x0; fu.w = hi ? c3 : x1;
      const bf16x8 pf = __builtin_bit_cast(bf16x8, fu);
      __builtin_amdgcn_s_setprio(1);
      acc0 = __builtin_amdgcn_mfma_f32_32x32x16_bf16(vf0, pf, acc0, 0, 0, 0);
      acc1 = __builtin_amdgcn_mfma_f32_32x32x16_bf16(vf1, pf, acc1, 0, 0, 0);
      __builtin_amdgcn_s_setprio(0);
    }
    {   // keys 16..31
      const unsigned c4 = cvtpk(st[8], st[9]),   c5 = cvtpk(st[10], st[11]);
      const unsigned c6 = cvtpk(st[12], st[13]), c7 = cvtpk(st[14], st[15]);
      const unsigned x4 = __shfl_xor(c4, 32), x5 = __shfl_xor(c5, 32);
      const unsigned x6 = __shfl_xor(c6, 32), x7 = __shfl_xor(c7, 32);
      u32x4 fu;
      fu.x = hi ? x6 : c4; fu.y = hi ? x7 : c5;
      fu.z = hi ? c6 : x4; fu.w = hi ? c7 : x5;
      const bf16x8 pf = __builtin_bit_cast(bf16x8, fu);
      __builtin_amdgcn_s_setprio(1);
      acc0 = __builtin_amdgcn_mfma_f32_32x32x16_bf16(vf2, pf, acc0, 0, 0, 0);
      acc1 = __builtin_amdgcn_mfma_f32_32x32x16_bf16(vf3, pf, acc1, 0, 0, 0);
      __builtin_amdgcn_s_setprio(0);
    }
    kc0 = kn0; kc1 = kn1; kc2 = kn2; kc3 = kn3;   // rotate prefetched K
  }

  // ---- K-half merge via LDS ----
#pragma unroll
  for (int r = 0; r < 16; r++) {
    smem[w][lane][r]      = acc0[r];
    smem[w][lane][16 + r] = acc1[r];
  }
  msh[w][lane] = m; lsh[w][lane] = l;
  __syncthreads();
  if (half) return;

  const int pw = w ^ 1;
  const float mB = msh[pw][lane], lB = lsh[pw][lane];
  const float mm = fmaxf(m, mB);
  float sA = exp2f(m - mm), sB = exp2f(mB - mm);
  const float linv = 1.f / (l * sA + lB * sB);
  sA *= linv; sB *= linv;

  unsigned* tp = (unsigned*)&smem[w][0][0];       // reuse own slot: [32][34] u32
  const float* pa = &smem[pw][lane][0];
#pragma unroll
  for (int j = 0; j < 8; j++) {
    const int wd = (j & 1) + 4 * (j >> 1) + 2 * hi;
    const float a0 = acc0[2 * j] * sA + pa[2 * j] * sB;
    const float b0 = acc0[2 * j + 1] * sA + pa[2 * j + 1] * sB;
    tp[ql * 34 + wd] = cvtpk(a0, b0);
    const float a1 = acc1[2 * j] * sA + pa[16 + 2 * j] * sB;
    const float b1 = acc1[2 * j + 1] * sA + pa[16 + 2 * j + 1] * sB;
    tp[ql * 34 + 16 + wd] = cvtpk(a1, b1);
  }
  // read rows back (lane -> row ql, half hi) and store coalesced
  unsigned* yu = (unsigned*)y;
  const size_t yrow = (size_t)(bb * S_LEN + q0 + ql) * (DIM / 2) + hh * (HDIM / 2) + hi * 16;
#pragma unroll
  for (int i = 0; i < 8; i++) {
    const uint2 d2 = *(const uint2*)&tp[ql * 34 + hi * 16 + 2 * i];
    *(uint2*)&yu[yrow + 2 * i] = d2;
  }
}

// ---------------- LayerNorm (row = 1024), OUTBF: 1 -> bf16, 0 -> f32 ---------
template <int OUTBF>
__global__ __launch_bounds__(256) void ln_k(const float* __restrict__ X,
                                            const float* __restrict__ g,
                                            const float* __restrict__ be,
                                            void* __restrict__ out) {
  const int row = blockIdx.x, t = threadIdx.x;
  const float4 v = ((const float4*)(X + (size_t)row * DIM))[t];
  float s  = v.x + v.y + v.z + v.w;
  float s2 = v.x * v.x + v.y * v.y + v.z * v.z + v.w * v.w;
#pragma unroll
  for (int o = 32; o >= 1; o >>= 1) {
    s  += __shfl_down(s, o);
    s2 += __shfl_down(s2, o);
  }
  __shared__ float red[8];
  if ((t & 63) == 0) { red[t >> 6] = s; red[4 + (t >> 6)] = s2; }
  __syncthreads();
  s  = red[0] + red[1] + red[2] + red[3];
  s2 = red[4] + red[5] + red[6] + red[7];
  const float mu  = s * (1.0f / DIM);
  const float var = s2 * (1.0f / DIM) - mu * mu;
  const float r   = rsqrtf(var + 1e-5f);
  const float4 gv = ((const float4*)g)[t];
  const float4 bv = ((const float4*)be)[t];
  const float o0 = (v.x - mu) * r * gv.x + bv.x;
  const float o1 = (v.y - mu) * r * gv.y + bv.y;
  const float o2 = (v.z - mu) * r * gv.z + bv.z;
  const float o3 = (v.w - mu) * r * gv.w + bv.w;
  if constexpr (OUTBF) {
    ushort4 p; p.x = f2bf(o0); p.y = f2bf(o1); p.z = f2bf(o2); p.w = f2bf(o3);
    ((ushort4*)out)[(size_t)row * 256 + t] = p;
  } else {
    float4 p; p.x = o0; p.y = o1; p.z = o2; p.w = o3;
    ((float4*)out)[(size_t)row * 256 + t] = p;
  }
}

// ---------------------------------------------------------------------------
extern "C" void kernel_launch(void* const* d_in, const int* in_sizes, int n_in,
                              void* d_out, int out_size, void* d_ws, size_t ws_size,
                              hipStream_t stream) {
  const float* x   = (const float*)d_in[0];
  const float* Wq  = (const float*)d_in[1];
  const float* bq  = (const float*)d_in[2];
  const float* Wk  = (const float*)d_in[3];
  const float* bk  = (const float*)d_in[4];
  const float* Wv  = (const float*)d_in[5];
  const float* bv  = (const float*)d_in[6];
  const float* Wp  = (const float*)d_in[7];
  const float* bp  = (const float*)d_in[8];
  const float* g0  = (const float*)d_in[9];
  const float* be0 = (const float*)d_in[10];
  const float* W1  = (const float*)d_in[11];
  const float* b1  = (const float*)d_in[12];
  const float* W2  = (const float*)d_in[13];
  const float* b2  = (const float*)d_in[14];
  const float* g1  = (const float*)d_in[15];
  const float* be1 = (const float*)d_in[16];

  char* ws = (char*)d_ws;
  const size_t MB = 1ull << 20;
  unsigned short* xb    = (unsigned short*)(ws + 0 * MB);   //  8 MB
  unsigned short* qkvb  = (unsigned short*)(ws + 8 * MB);   // 24 MB [4096][3072]
  unsigned short* vTb   = (unsigned short*)(ws + 32 * MB);  //  8 MB
  unsigned short* yb    = (unsigned short*)(ws + 40 * MB);  //  8 MB
  float*          bqkv  = (float*)(ws + 48 * MB);           // 12 KB (dead before x1 write)
  float*          x1    = (float*)(ws + 48 * MB);           // 16 MB
  unsigned short* hb    = (unsigned short*)(ws + 64 * MB);  //  8 MB
  unsigned short* WqkvT = (unsigned short*)(ws + 72 * MB);  //  6 MB [3072][1024]
  unsigned short* WpT   = (unsigned short*)(ws + 78 * MB);  //  2 MB
  unsigned short* W1T   = (unsigned short*)(ws + 80 * MB);  //  8 MB
  unsigned short* W2T   = (unsigned short*)(ws + 88 * MB);  //  8 MB -> 96 MB
  unsigned short* h1    = (unsigned short*)(ws + 8 * MB);   // 32 MB alias qkvb+vTb (dead)
  float*          x2    = (float*)(ws + 64 * MB);           // 16 MB alias hb+WqkvT+WpT (dead)

  // 1) casts / transposes (Q weights+bias pre-scaled by 0.125*log2e)
  cast_f32_bf16<<<2048, 256, 0, stream>>>(x, xb);
  tcast_k<<<dim3(32, 32), 256, 0, stream>>>(Wq, WqkvT,               1024, 1024, QS);
  tcast_k<<<dim3(32, 32), 256, 0, stream>>>(Wk, WqkvT + 1024 * 1024, 1024, 1024, 1.f);
  tcast_k<<<dim3(32, 32), 256, 0, stream>>>(Wv, WqkvT + 2048 * 1024, 1024, 1024, 1.f);
  tcast_k<<<dim3(32, 32), 256, 0, stream>>>(Wp, WpT, 1024, 1024, 1.f);
  tcast_k<<<dim3(128, 32), 256, 0, stream>>>(W1, W1T, 1024, 4096, 1.f);
  tcast_k<<<dim3(32, 128), 256, 0, stream>>>(W2, W2T, 4096, 1024, 1.f);
  bcat_k<<<12, 256, 0, stream>>>(bq, bk, bv, bqkv);

  // 2) fused QKV projection: [4096][3072]
  gemm_bt<0><<<dim3(24, 32), 256, 0, stream>>>(xb, WqkvT, bqkv, nullptr, qkvb, MTOK, 3072, 1024);

  // 3) attention
  vtrans_k<<<dim3(32, 32), 256, 0, stream>>>(qkvb, vTb);
  attn32_k<<<dim3(32, 32), 256, 0, stream>>>(qkvb, vTb, yb);

  // 4) out-proj + residual (fp32), LN1 -> bf16
  gemm_bt<2><<<dim3(8, 32), 256, 0, stream>>>(yb, WpT, bp, x, x1, MTOK, DIM, DIM);
  ln_k<1><<<4096, 256, 0, stream>>>(x1, g0, be0, hb);

  // 5) MLP: gelu(h@W1+b1) -> h1 ; h1@W2+b2 + x1 -> x2 ; LN2 -> out (f32)
  gemm_bt<1><<<dim3(32, 32), 256, 0, stream>>>(hb, W1T, b1, nullptr, h1, MTOK, DFF, DIM);
  gemm_bt<2><<<dim3(8, 32), 256, 0, stream>>>(h1, W2T, b2, x1, x2, MTOK, DIM, DFF);
  ln_k<0><<<4096, 256, 0, stream>>>(x2, g1, be1, d_out);
}

// Round 6
// 471.755 us; speedup vs baseline: 1.3963x; 1.1172x over previous
//
#include <hip/hip_runtime.h>
#include <stdint.h>

// Problem dims (fixed)
#define S_LEN 2048
#define DIM   1024
#define NH    16
#define HDIM  64
#define MTOK  4096   // B*S
#define DFF   4096

#define QS 0.18033688011112042f   // 0.125 * log2(e): attn uses exp2

typedef short bf16x8 __attribute__((ext_vector_type(8)));
typedef float f32x4  __attribute__((ext_vector_type(4)));
typedef float f32x16 __attribute__((ext_vector_type(16)));
typedef unsigned int u32x4 __attribute__((ext_vector_type(4)));

__device__ __forceinline__ unsigned short f2bf(float f) {
  unsigned int u = __float_as_uint(f);
  u += 0x7fffu + ((u >> 16) & 1u);          // RNE
  return (unsigned short)(u >> 16);
}

__device__ __forceinline__ unsigned cvtpk(float a, float b) {
  unsigned r;
  asm("v_cvt_pk_bf16_f32 %0, %1, %2" : "=v"(r) : "v"(a), "v"(b));
  return r;
}

__device__ __forceinline__ float gelu_f(float x) {
  const float c = 0.7978845608028654f;       // sqrt(2/pi)
  float u = c * (x + 0.044715f * x * x * x);
  return 0.5f * x * (1.0f + tanhf(u));
}

__device__ __forceinline__ void gld_lds16(const void* g, void* lds) {
  using gu32p = __attribute__((address_space(1))) unsigned int*;
  using lu32p = __attribute__((address_space(3))) unsigned int*;
  __builtin_amdgcn_global_load_lds((gu32p)g, (lu32p)lds, 16, 0, 0);
}

// ---------------- cast fp32 -> bf16 (vectorized, 8 elems/thread) -------------
__global__ __launch_bounds__(256) void cast_f32_bf16(const float* __restrict__ x,
                                                     unsigned short* __restrict__ xb) {
  const size_t i = (size_t)blockIdx.x * 256 + threadIdx.x;
  const float4 a = ((const float4*)x)[2 * i];
  const float4 b = ((const float4*)x)[2 * i + 1];
  ushort4 p0, p1;
  p0.x = f2bf(a.x); p0.y = f2bf(a.y); p0.z = f2bf(a.z); p0.w = f2bf(a.w);
  p1.x = f2bf(b.x); p1.y = f2bf(b.y); p1.z = f2bf(b.z); p1.w = f2bf(b.w);
  ((ushort4*)xb)[2 * i]     = p0;
  ((ushort4*)xb)[2 * i + 1] = p1;
}

// ------------- transpose+cast+scale: W[K][N] f32 -> Wt[N][K] bf16 ------------
__global__ __launch_bounds__(256) void tcast_k(const float* __restrict__ W,
                                               unsigned short* __restrict__ Wt,
                                               int K, int N, float scale) {
  __shared__ float tile[32][33];
  const int tx = threadIdx.x & 31, ty = threadIdx.x >> 5;
  const int n0 = blockIdx.x * 32, k0 = blockIdx.y * 32;
#pragma unroll
  for (int i = 0; i < 4; i++)
    tile[ty + 8 * i][tx] = W[(size_t)(k0 + ty + 8 * i) * N + n0 + tx];
  __syncthreads();
#pragma unroll
  for (int i = 0; i < 4; i++)
    Wt[(size_t)(n0 + ty + 8 * i) * K + k0 + tx] = f2bf(tile[tx][ty + 8 * i] * scale);
}

// ------------- concat (+scale q) biases into bqkv[3072] ----------------------
__global__ __launch_bounds__(256) void bcat_k(const float* __restrict__ bq,
                                              const float* __restrict__ bk,
                                              const float* __restrict__ bv,
                                              float* __restrict__ bqkv) {
  const int t = blockIdx.x * 256 + threadIdx.x;
  float v;
  if (t < 1024)      v = bq[t] * QS;
  else if (t < 2048) v = bk[t - 1024];
  else               v = bv[t - 2048];
  bqkv[t] = v;
}

// ------------- transpose V (inside qkv, stride 3072) -> vT[(b,h,d)][s] -------
__global__ __launch_bounds__(256) void vtrans_k(const unsigned short* __restrict__ qkv,
                                                unsigned short* __restrict__ vT) {
  __shared__ unsigned short tile[64][65];
  const int bh = blockIdx.y, b = bh >> 4, h = bh & 15;
  const int s0 = blockIdx.x * 64;
  const int t = threadIdx.x;
#pragma unroll
  for (int i = 0; i < 16; i++) {
    int idx = i * 256 + t, r = idx >> 6, c = idx & 63;
    tile[r][c] = qkv[(size_t)(b * S_LEN + s0 + r) * 3072 + 2048 + h * HDIM + c];
  }
  __syncthreads();
#pragma unroll
  for (int i = 0; i < 16; i++) {
    int idx = i * 256 + t, d = idx >> 6, s = idx & 63;
    vT[(size_t)(bh * HDIM + d) * S_LEN + s0 + s] = tile[s][d];
  }
}

// ---------------- GEMM: C = A[M,K](bf16) * Bt[N,K]^T(bf16) + bias ------------
// EPI: 0 = bf16 out, 1 = bf16 gelu out, 2 = f32 out + resid add
template <int EPI>
__global__ __launch_bounds__(256) void gemm_bt(const unsigned short* __restrict__ A,
                                               const unsigned short* __restrict__ Bt,
                                               const float* __restrict__ bias,
                                               const float* __restrict__ resid,
                                               void* __restrict__ Cout,
                                               int M, int N, int K) {
  __shared__ alignas(16) short As[128 * 32];
  __shared__ alignas(16) short Bs[128 * 32];
  const int t = threadIdx.x;
  const int w = t >> 6, lane = t & 63;
  const int m0 = blockIdx.y * 128, n0 = blockIdx.x * 128;
  const int wr = (w >> 1) * 64, wc = (w & 1) * 64;
  const int lr = lane & 15, lg = lane >> 4;

  f32x4 acc[4][4] = {};

  const int off0 = w * 2048 + lane * 16;        // byte offset in 8KB tile
  const int r0 = off0 >> 6, c0 = (off0 & 63) >> 1;
  const int off1 = off0 + 1024;
  const int r1 = off1 >> 6, c1 = (off1 & 63) >> 1;

  const unsigned short* Ag0 = A + (size_t)(m0 + r0) * K + c0;
  const unsigned short* Ag1 = A + (size_t)(m0 + r1) * K + c1;
  const unsigned short* Bg0 = Bt + (size_t)(n0 + r0) * K + c0;
  const unsigned short* Bg1 = Bt + (size_t)(n0 + r1) * K + c1;
  char* AsB = (char*)As;
  char* BsB = (char*)Bs;

  for (int k0 = 0; k0 < K; k0 += 32) {
    gld_lds16(Ag0 + k0, AsB + w * 2048);
    gld_lds16(Ag1 + k0, AsB + w * 2048 + 1024);
    gld_lds16(Bg0 + k0, BsB + w * 2048);
    gld_lds16(Bg1 + k0, BsB + w * 2048 + 1024);
    __syncthreads();
    bf16x8 af[4], bfr[4];
#pragma unroll
    for (int i = 0; i < 4; i++) {
      af[i]  = *reinterpret_cast<const bf16x8*>(As + (wr + i * 16 + lr) * 32 + lg * 8);
      bfr[i] = *reinterpret_cast<const bf16x8*>(Bs + (wc + i * 16 + lr) * 32 + lg * 8);
    }
#pragma unroll
    for (int mi = 0; mi < 4; mi++)
#pragma unroll
      for (int ni = 0; ni < 4; ni++)
        acc[mi][ni] = __builtin_amdgcn_mfma_f32_16x16x32_bf16(af[mi], bfr[ni],
                                                              acc[mi][ni], 0, 0, 0);
    __syncthreads();
  }

  // epilogue: D layout col = lane&15, row = (lane>>4)*4 + j
  const int colb = n0 + wc + lr;
  const int rowb = m0 + wr + lg * 4;
#pragma unroll
  for (int ni = 0; ni < 4; ni++) {
    const int col = colb + ni * 16;
    const float bv = bias[col];
#pragma unroll
    for (int mi = 0; mi < 4; mi++) {
#pragma unroll
      for (int j = 0; j < 4; j++) {
        const int row = rowb + mi * 16 + j;
        const size_t idx = (size_t)row * N + col;
        float v = acc[mi][ni][j] + bv;
        if constexpr (EPI == 0) {
          ((unsigned short*)Cout)[idx] = f2bf(v);
        } else if constexpr (EPI == 1) {
          ((unsigned short*)Cout)[idx] = f2bf(gelu_f(v));
        } else {
          ((float*)Cout)[idx] = v + resid[idx];
        }
      }
    }
  }
}

// ---------------- causal flash attention, 32x32 MFMA, swapped QK^T -----------
// 2-wave blocks: one 32-row q-tile per block, wave = key-tile parity half.
// Grid (bh fast, q-tile slow) so a CU's resident blocks span light AND heavy
// q-tiles (round-robin bid->CU stride would otherwise give one CU all-heavy
// tiles: that imbalance was 128 us in round 4). Same-bh blocks share an XCD
// -> K/V L2-resident per head. In-register softmax (q = lane&31), defer-max,
// exp2 logits (Q pre-scaled). K prefetched one tile ahead; V loads hoisted.
__global__ __launch_bounds__(128) void attn32_k(const unsigned short* __restrict__ qkv,
                                                const unsigned short* __restrict__ vT,
                                                unsigned short* __restrict__ y) {
  __shared__ float smem[2][64][33];
  __shared__ float msh[2][64], lsh[2][64];

  const int t = threadIdx.x, w = t >> 6, lane = t & 63;
  const int ql = lane & 31, hi = lane >> 5;
  const int bh = blockIdx.x, bb = bh >> 4, hh = bh & 15;
  const int qt = 63 - blockIdx.y;                    // heavy tiles first
  const int half = w;
  const int q0 = qt * 32;

  // Q fragments (B-operand): Q[q0+ql][hh*64 + ks*16 + hi*8 + i]
  const unsigned short* qp = qkv + (size_t)(bb * S_LEN + q0 + ql) * 3072 + hh * HDIM + hi * 8;
  const bf16x8 qf0 = *(const bf16x8*)(qp);
  const bf16x8 qf1 = *(const bf16x8*)(qp + 16);
  const bf16x8 qf2 = *(const bf16x8*)(qp + 32);
  const bf16x8 qf3 = *(const bf16x8*)(qp + 48);

  const unsigned short* kbp = qkv + (size_t)(bb * S_LEN) * 3072 + 1024 + hh * HDIM + hi * 8;
  const unsigned short* vbp = vT + (size_t)(bh * HDIM + ql) * (size_t)S_LEN + hi * 8;

  f32x16 acc0 = {}, acc1 = {};
  float m = -1e30f, l = 0.f;

  const int start = half * 32;

  // K prologue load (tile at `start`; rows < S_LEN even when loop is empty)
  const unsigned short* kp0 = kbp + (size_t)(start + ql) * 3072;
  bf16x8 kc0 = *(const bf16x8*)(kp0);
  bf16x8 kc1 = *(const bf16x8*)(kp0 + 16);
  bf16x8 kc2 = *(const bf16x8*)(kp0 + 32);
  bf16x8 kc3 = *(const bf16x8*)(kp0 + 48);

  for (int t0 = start; t0 <= q0; t0 += 64) {
    // V current-tile loads issue first; softmax below covers their latency
    const unsigned short* vp = vbp + t0;
    const bf16x8 vf0 = *(const bf16x8*)(vp);
    const bf16x8 vf1 = *(const bf16x8*)(vp + 32 * S_LEN);
    const bf16x8 vf2 = *(const bf16x8*)(vp + 16);
    const bf16x8 vf3 = *(const bf16x8*)(vp + 32 * S_LEN + 16);

    // S^T[key][q] = K · Q^T   (keys = rows)
    __builtin_amdgcn_s_setprio(1);
    f32x16 st = {};
    st = __builtin_amdgcn_mfma_f32_32x32x16_bf16(kc0, qf0, st, 0, 0, 0);
    st = __builtin_amdgcn_mfma_f32_32x32x16_bf16(kc1, qf1, st, 0, 0, 0);
    st = __builtin_amdgcn_mfma_f32_32x32x16_bf16(kc2, qf2, st, 0, 0, 0);
    st = __builtin_amdgcn_mfma_f32_32x32x16_bf16(kc3, qf3, st, 0, 0, 0);
    __builtin_amdgcn_s_setprio(0);

    // K prefetch for t0+64 (clamped in-bounds on final iteration)
    const int t1 = (t0 + 64 <= q0) ? (t0 + 64) : t0;
    const unsigned short* kpn = kbp + (size_t)(t1 + ql) * 3072;
    const bf16x8 kn0 = *(const bf16x8*)(kpn);
    const bf16x8 kn1 = *(const bf16x8*)(kpn + 16);
    const bf16x8 kn2 = *(const bf16x8*)(kpn + 32);
    const bf16x8 kn3 = *(const bf16x8*)(kpn + 48);

    if (t0 == q0) {                         // diagonal tile: causal mask
#pragma unroll
      for (int r = 0; r < 16; r++) {
        const int key = (r & 3) + 8 * (r >> 2) + 4 * hi;
        if (key > ql) st[r] = -1e30f;
      }
    }
    float pm = st[0];
#pragma unroll
    for (int r = 1; r < 16; r++) pm = fmaxf(pm, st[r]);
    pm = fmaxf(pm, __shfl_xor(pm, 32));
    if (!__all(pm - m <= 8.f)) {            // defer-max (T13)
      const float mn = fmaxf(m, pm);
      const float rs = exp2f(m - mn);
      l *= rs;
#pragma unroll
      for (int r = 0; r < 16; r++) { acc0[r] *= rs; acc1[r] *= rs; }
      m = mn;
    }
    float sum = 0.f;
#pragma unroll
    for (int r = 0; r < 16; r++) { st[r] = exp2f(st[r] - m); sum += st[r]; }
    sum += __shfl_xor(sum, 32);
    l += sum;

    {   // P^T B-frag, keys 0..15 of tile
      const unsigned c0 = cvtpk(st[0], st[1]), c1 = cvtpk(st[2], st[3]);
      const unsigned c2 = cvtpk(st[4], st[5]), c3 = cvtpk(st[6], st[7]);
      const unsigned x0 = __shfl_xor(c0, 32), x1 = __shfl_xor(c1, 32);
      const unsigned x2 = __shfl_xor(c2, 32), x3 = __shfl_xor(c3, 32);
      u32x4 fu;
      fu.x = hi ? x2 : c0; fu.y = hi ? x3 : c1;
      fu.z = hi ? c2 : x0; fu.w = hi ? c3 : x1;
      const bf16x8 pf = __builtin_bit_cast(bf16x8, fu);
      __builtin_amdgcn_s_setprio(1);
      acc0 = __builtin_amdgcn_mfma_f32_32x32x16_bf16(vf0, pf, acc0, 0, 0, 0);
      acc1 = __builtin_amdgcn_mfma_f32_32x32x16_bf16(vf1, pf, acc1, 0, 0, 0);
      __builtin_amdgcn_s_setprio(0);
    }
    {   // keys 16..31
      const unsigned c4 = cvtpk(st[8], st[9]),   c5 = cvtpk(st[10], st[11]);
      const unsigned c6 = cvtpk(st[12], st[13]), c7 = cvtpk(st[14], st[15]);
      const unsigned x4 = __shfl_xor(c4, 32), x5 = __shfl_xor(c5, 32);
      const unsigned x6 = __shfl_xor(c6, 32), x7 = __shfl_xor(c7, 32);
      u32x4 fu;
      fu.x = hi ? x6 : c4; fu.y = hi ? x7 : c5;
      fu.z = hi ? c6 : x4; fu.w = hi ? c7 : x5;
      const bf16x8 pf = __builtin_bit_cast(bf16x8, fu);
      __builtin_amdgcn_s_setprio(1);
      acc0 = __builtin_amdgcn_mfma_f32_32x32x16_bf16(vf2, pf, acc0, 0, 0, 0);
      acc1 = __builtin_amdgcn_mfma_f32_32x32x16_bf16(vf3, pf, acc1, 0, 0, 0);
      __builtin_amdgcn_s_setprio(0);
    }
    kc0 = kn0; kc1 = kn1; kc2 = kn2; kc3 = kn3;   // rotate prefetched K
  }

  // ---- K-half merge via LDS ----
#pragma unroll
  for (int r = 0; r < 16; r++) {
    smem[w][lane][r]      = acc0[r];
    smem[w][lane][16 + r] = acc1[r];
  }
  msh[w][lane] = m; lsh[w][lane] = l;
  __syncthreads();
  if (half) return;

  const int pw = w ^ 1;
  const float mB = msh[pw][lane], lB = lsh[pw][lane];
  const float mm = fmaxf(m, mB);
  float sA = exp2f(m - mm), sB = exp2f(mB - mm);
  const float linv = 1.f / (l * sA + lB * sB);
  sA *= linv; sB *= linv;

  unsigned* tp = (unsigned*)&smem[w][0][0];       // reuse own slot: [32][34] u32
  const float* pa = &smem[pw][lane][0];
#pragma unroll
  for (int j = 0; j < 8; j++) {
    const int wd = (j & 1) + 4 * (j >> 1) + 2 * hi;
    const float a0 = acc0[2 * j] * sA + pa[2 * j] * sB;
    const float b0 = acc0[2 * j + 1] * sA + pa[2 * j + 1] * sB;
    tp[ql * 34 + wd] = cvtpk(a0, b0);
    const float a1 = acc1[2 * j] * sA + pa[16 + 2 * j] * sB;
    const float b1 = acc1[2 * j + 1] * sA + pa[16 + 2 * j + 1] * sB;
    tp[ql * 34 + 16 + wd] = cvtpk(a1, b1);
  }
  // read rows back (lane -> row ql, half hi) and store coalesced
  unsigned* yu = (unsigned*)y;
  const size_t yrow = (size_t)(bb * S_LEN + q0 + ql) * (DIM / 2) + hh * (HDIM / 2) + hi * 16;
#pragma unroll
  for (int i = 0; i < 8; i++) {
    const uint2 d2 = *(const uint2*)&tp[ql * 34 + hi * 16 + 2 * i];
    *(uint2*)&yu[yrow + 2 * i] = d2;
  }
}

// ---------------- LayerNorm (row = 1024), OUTBF: 1 -> bf16, 0 -> f32 ---------
template <int OUTBF>
__global__ __launch_bounds__(256) void ln_k(const float* __restrict__ X,
                                            const float* __restrict__ g,
                                            const float* __restrict__ be,
                                            void* __restrict__ out) {
  const int row = blockIdx.x, t = threadIdx.x;
  const float4 v = ((const float4*)(X + (size_t)row * DIM))[t];
  float s  = v.x + v.y + v.z + v.w;
  float s2 = v.x * v.x + v.y * v.y + v.z * v.z + v.w * v.w;
#pragma unroll
  for (int o = 32; o >= 1; o >>= 1) {
    s  += __shfl_down(s, o);
    s2 += __shfl_down(s2, o);
  }
  __shared__ float red[8];
  if ((t & 63) == 0) { red[t >> 6] = s; red[4 + (t >> 6)] = s2; }
  __syncthreads();
  s  = red[0] + red[1] + red[2] + red[3];
  s2 = red[4] + red[5] + red[6] + red[7];
  const float mu  = s * (1.0f / DIM);
  const float var = s2 * (1.0f / DIM) - mu * mu;
  const float r   = rsqrtf(var + 1e-5f);
  const float4 gv = ((const float4*)g)[t];
  const float4 bv = ((const float4*)be)[t];
  const float o0 = (v.x - mu) * r * gv.x + bv.x;
  const float o1 = (v.y - mu) * r * gv.y + bv.y;
  const float o2 = (v.z - mu) * r * gv.z + bv.z;
  const float o3 = (v.w - mu) * r * gv.w + bv.w;
  if constexpr (OUTBF) {
    ushort4 p; p.x = f2bf(o0); p.y = f2bf(o1); p.z = f2bf(o2); p.w = f2bf(o3);
    ((ushort4*)out)[(size_t)row * 256 + t] = p;
  } else {
    float4 p; p.x = o0; p.y = o1; p.z = o2; p.w = o3;
    ((float4*)out)[(size_t)row * 256 + t] = p;
  }
}

// ---------------------------------------------------------------------------
extern "C" void kernel_launch(void* const* d_in, const int* in_sizes, int n_in,
                              void* d_out, int out_size, void* d_ws, size_t ws_size,
                              hipStream_t stream) {
  const float* x   = (const float*)d_in[0];
  const float* Wq  = (const float*)d_in[1];
  const float* bq  = (const float*)d_in[2];
  const float* Wk  = (const float*)d_in[3];
  const float* bk  = (const float*)d_in[4];
  const float* Wv  = (const float*)d_in[5];
  const float* bv  = (const float*)d_in[6];
  const float* Wp  = (const float*)d_in[7];
  const float* bp  = (const float*)d_in[8];
  const float* g0  = (const float*)d_in[9];
  const float* be0 = (const float*)d_in[10];
  const float* W1  = (const float*)d_in[11];
  const float* b1  = (const float*)d_in[12];
  const float* W2  = (const float*)d_in[13];
  const float* b2  = (const float*)d_in[14];
  const float* g1  = (const float*)d_in[15];
  const float* be1 = (const float*)d_in[16];

  char* ws = (char*)d_ws;
  const size_t MB = 1ull << 20;
  unsigned short* xb    = (unsigned short*)(ws + 0 * MB);   //  8 MB
  unsigned short* qkvb  = (unsigned short*)(ws + 8 * MB);   // 24 MB [4096][3072]
  unsigned short* vTb   = (unsigned short*)(ws + 32 * MB);  //  8 MB
  unsigned short* yb    = (unsigned short*)(ws + 40 * MB);  //  8 MB
  float*          bqkv  = (float*)(ws + 48 * MB);           // 12 KB (dead before x1 write)
  float*          x1    = (float*)(ws + 48 * MB);           // 16 MB
  unsigned short* hb    = (unsigned short*)(ws + 64 * MB);  //  8 MB
  unsigned short* WqkvT = (unsigned short*)(ws + 72 * MB);  //  6 MB [3072][1024]
  unsigned short* WpT   = (unsigned short*)(ws + 78 * MB);  //  2 MB
  unsigned short* W1T   = (unsigned short*)(ws + 80 * MB);  //  8 MB
  unsigned short* W2T   = (unsigned short*)(ws + 88 * MB);  //  8 MB -> 96 MB
  unsigned short* h1    = (unsigned short*)(ws + 8 * MB);   // 32 MB alias qkvb+vTb (dead)
  float*          x2    = (float*)(ws + 64 * MB);           // 16 MB alias hb+WqkvT+WpT (dead)

  // 1) casts / transposes (Q weights+bias pre-scaled by 0.125*log2e)
  cast_f32_bf16<<<2048, 256, 0, stream>>>(x, xb);
  tcast_k<<<dim3(32, 32), 256, 0, stream>>>(Wq, WqkvT,               1024, 1024, QS);
  tcast_k<<<dim3(32, 32), 256, 0, stream>>>(Wk, WqkvT + 1024 * 1024, 1024, 1024, 1.f);
  tcast_k<<<dim3(32, 32), 256, 0, stream>>>(Wv, WqkvT + 2048 * 1024, 1024, 1024, 1.f);
  tcast_k<<<dim3(32, 32), 256, 0, stream>>>(Wp, WpT, 1024, 1024, 1.f);
  tcast_k<<<dim3(128, 32), 256, 0, stream>>>(W1, W1T, 1024, 4096, 1.f);
  tcast_k<<<dim3(32, 128), 256, 0, stream>>>(W2, W2T, 4096, 1024, 1.f);
  bcat_k<<<12, 256, 0, stream>>>(bq, bk, bv, bqkv);

  // 2) fused QKV projection: [4096][3072]
  gemm_bt<0><<<dim3(24, 32), 256, 0, stream>>>(xb, WqkvT, bqkv, nullptr, qkvb, MTOK, 3072, 1024);

  // 3) attention (bh fast dim for per-CU qt balance + per-XCD head locality)
  vtrans_k<<<dim3(32, 32), 256, 0, stream>>>(qkvb, vTb);
  attn32_k<<<dim3(32, 64), 128, 0, stream>>>(qkvb, vTb, yb);

  // 4) out-proj + residual (fp32), LN1 -> bf16
  gemm_bt<2><<<dim3(8, 32), 256, 0, stream>>>(yb, WpT, bp, x, x1, MTOK, DIM, DIM);
  ln_k<1><<<4096, 256, 0, stream>>>(x1, g0, be0, hb);

  // 5) MLP: gelu(h@W1+b1) -> h1 ; h1@W2+b2 + x1 -> x2 ; LN2 -> out (f32)
  gemm_bt<1><<<dim3(32, 32), 256, 0, stream>>>(hb, W1T, b1, nullptr, h1, MTOK, DFF, DIM);
  gemm_bt<2><<<dim3(8, 32), 256, 0, stream>>>(h1, W2T, b2, x1, x2, MTOK, DIM, DFF);
  ln_k<0><<<4096, 256, 0, stream>>>(x2, g1, be1, d_out);
}

// Round 7
// 462.128 us; speedup vs baseline: 1.4254x; 1.0208x over previous
//
#include <hip/hip_runtime.h>
#include <stdint.h>

// Problem dims (fixed)
#define S_LEN 2048
#define DIM   1024
#define NH    16
#define HDIM  64
#define MTOK  4096   // B*S
#define DFF   4096

#define QS 0.18033688011112042f   // 0.125 * log2(e): attn uses exp2

typedef short bf16x8 __attribute__((ext_vector_type(8)));
typedef float f32x4  __attribute__((ext_vector_type(4)));
typedef float f32x16 __attribute__((ext_vector_type(16)));
typedef unsigned int u32x4 __attribute__((ext_vector_type(4)));

__device__ __forceinline__ unsigned short f2bf(float f) {
  unsigned int u = __float_as_uint(f);
  u += 0x7fffu + ((u >> 16) & 1u);          // RNE
  return (unsigned short)(u >> 16);
}

__device__ __forceinline__ unsigned cvtpk(float a, float b) {
  unsigned r;
  asm("v_cvt_pk_bf16_f32 %0, %1, %2" : "=v"(r) : "v"(a), "v"(b));
  return r;
}

__device__ __forceinline__ float gelu_f(float x) {
  const float c = 0.7978845608028654f;       // sqrt(2/pi)
  float u = c * (x + 0.044715f * x * x * x);
  return 0.5f * x * (1.0f + tanhf(u));
}

__device__ __forceinline__ void gld_lds16(const void* g, void* lds) {
  using gu32p = __attribute__((address_space(1))) unsigned int*;
  using lu32p = __attribute__((address_space(3))) unsigned int*;
  __builtin_amdgcn_global_load_lds((gu32p)g, (lu32p)lds, 16, 0, 0);
}

// ---------------- cast fp32 -> bf16 (vectorized, 8 elems/thread) -------------
__global__ __launch_bounds__(256) void cast_f32_bf16(const float* __restrict__ x,
                                                     unsigned short* __restrict__ xb) {
  const size_t i = (size_t)blockIdx.x * 256 + threadIdx.x;
  const float4 a = ((const float4*)x)[2 * i];
  const float4 b = ((const float4*)x)[2 * i + 1];
  ushort4 p0, p1;
  p0.x = f2bf(a.x); p0.y = f2bf(a.y); p0.z = f2bf(a.z); p0.w = f2bf(a.w);
  p1.x = f2bf(b.x); p1.y = f2bf(b.y); p1.z = f2bf(b.z); p1.w = f2bf(b.w);
  ((ushort4*)xb)[2 * i]     = p0;
  ((ushort4*)xb)[2 * i + 1] = p1;
}

// ------------- transpose+cast+scale: W[K][N] f32 -> Wt[N][K] bf16 ------------
__global__ __launch_bounds__(256) void tcast_k(const float* __restrict__ W,
                                               unsigned short* __restrict__ Wt,
                                               int K, int N, float scale) {
  __shared__ float tile[32][33];
  const int tx = threadIdx.x & 31, ty = threadIdx.x >> 5;
  const int n0 = blockIdx.x * 32, k0 = blockIdx.y * 32;
#pragma unroll
  for (int i = 0; i < 4; i++)
    tile[ty + 8 * i][tx] = W[(size_t)(k0 + ty + 8 * i) * N + n0 + tx];
  __syncthreads();
#pragma unroll
  for (int i = 0; i < 4; i++)
    Wt[(size_t)(n0 + ty + 8 * i) * K + k0 + tx] = f2bf(tile[tx][ty + 8 * i] * scale);
}

// ------------- concat (+scale q) biases into bqkv[3072] ----------------------
__global__ __launch_bounds__(256) void bcat_k(const float* __restrict__ bq,
                                              const float* __restrict__ bk,
                                              const float* __restrict__ bv,
                                              float* __restrict__ bqkv) {
  const int t = blockIdx.x * 256 + threadIdx.x;
  float v;
  if (t < 1024)      v = bq[t] * QS;
  else if (t < 2048) v = bk[t - 1024];
  else               v = bv[t - 2048];
  bqkv[t] = v;
}

// ------------- transpose V (inside qkv, stride 3072) -> vT[(b,h,d)][s] -------
__global__ __launch_bounds__(256) void vtrans_k(const unsigned short* __restrict__ qkv,
                                                unsigned short* __restrict__ vT) {
  __shared__ unsigned short tile[64][65];
  const int bh = blockIdx.y, b = bh >> 4, h = bh & 15;
  const int s0 = blockIdx.x * 64;
  const int t = threadIdx.x;
#pragma unroll
  for (int i = 0; i < 16; i++) {
    int idx = i * 256 + t, r = idx >> 6, c = idx & 63;
    tile[r][c] = qkv[(size_t)(b * S_LEN + s0 + r) * 3072 + 2048 + h * HDIM + c];
  }
  __syncthreads();
#pragma unroll
  for (int i = 0; i < 16; i++) {
    int idx = i * 256 + t, d = idx >> 6, s = idx & 63;
    vT[(size_t)(bh * HDIM + d) * S_LEN + s0 + s] = tile[s][d];
  }
}

// ------- 2-phase double-buffered GEMM: C = A[M,K] * Bt[N,K]^T + bias ---------
// T3 minimum recipe: BK=64, 2x(A,B) LDS buffers (64KB), per K-tile issue next
// tile's global_load_lds FIRST, then ds_read+MFMA of current, then ONE
// __syncthreads (vmcnt drain lands after 32 MFMAs, not before them).
// XCD-bijective block swizzle (T1); all grids used have nwg % 8 == 0.
// EPI: 0 = bf16 out, 1 = bf16 gelu out, 2 = f32 out + resid add
template <int EPI>
__global__ __launch_bounds__(256, 2) void gemm2p(const unsigned short* __restrict__ A,
                                                 const unsigned short* __restrict__ Bt,
                                                 const float* __restrict__ bias,
                                                 const float* __restrict__ resid,
                                                 void* __restrict__ Cout,
                                                 int M, int N, int K) {
  __shared__ alignas(16) short As[2][128 * 64];
  __shared__ alignas(16) short Bs[2][128 * 64];
  const int t = threadIdx.x, w = t >> 6, lane = t & 63;

  const int gx = gridDim.x, nwg = gx * gridDim.y;
  const int bid = blockIdx.x + gx * blockIdx.y;
  const int swz = (bid & 7) * (nwg >> 3) + (bid >> 3);   // bijective (nwg%8==0)
  const int m0 = (swz / gx) * 128, n0 = (swz % gx) * 128;

  const int wr = (w >> 1) * 64, wc = (w & 1) * 64;
  const int lr = lane & 15, lg = lane >> 4;

  f32x4 acc[4][4] = {};

  // staging: wave w stages rows [w*32, w*32+32), 4 chunks of 1KB each;
  // lane's 16B: row = w*32 + i*8 + (lane>>3), col = (lane&7)*8  (K-contig)
  const int sr = w * 32 + (lane >> 3);
  const int sc = (lane & 7) * 8;
  const unsigned short* Ag = A + (size_t)(m0 + sr) * K + sc;
  const unsigned short* Bg = Bt + (size_t)(n0 + sr) * K + sc;
  const int dbase = w * 4096 + lane * 16;   // byte offset within 16KB tile

  const int NT = K >> 6;   // BK = 64

  // prologue: stage tile 0 -> buf 0
#pragma unroll
  for (int i = 0; i < 4; i++) {
    gld_lds16(Ag + (size_t)(i * 8) * K, (char*)As[0] + dbase + i * 1024);
    gld_lds16(Bg + (size_t)(i * 8) * K, (char*)Bs[0] + dbase + i * 1024);
  }
  __syncthreads();

  int cur = 0;
  for (int kt = 0; kt < NT; ++kt) {
    if (kt + 1 < NT) {                       // issue next-tile loads FIRST
      const int k1 = (kt + 1) << 6;
#pragma unroll
      for (int i = 0; i < 4; i++) {
        gld_lds16(Ag + (size_t)(i * 8) * K + k1, (char*)As[cur ^ 1] + dbase + i * 1024);
        gld_lds16(Bg + (size_t)(i * 8) * K + k1, (char*)Bs[cur ^ 1] + dbase + i * 1024);
      }
    }
    bf16x8 af[2][4], bfr[2][4];
#pragma unroll
    for (int ks = 0; ks < 2; ks++)
#pragma unroll
      for (int i = 0; i < 4; i++) {
        af[ks][i]  = *reinterpret_cast<const bf16x8*>(&As[cur][(wr + i * 16 + lr) * 64 + ks * 32 + lg * 8]);
        bfr[ks][i] = *reinterpret_cast<const bf16x8*>(&Bs[cur][(wc + i * 16 + lr) * 64 + ks * 32 + lg * 8]);
      }
    __builtin_amdgcn_s_setprio(1);
#pragma unroll
    for (int ks = 0; ks < 2; ks++)
#pragma unroll
      for (int mi = 0; mi < 4; mi++)
#pragma unroll
        for (int ni = 0; ni < 4; ni++)
          acc[mi][ni] = __builtin_amdgcn_mfma_f32_16x16x32_bf16(af[ks][mi], bfr[ks][ni],
                                                                acc[mi][ni], 0, 0, 0);
    __builtin_amdgcn_s_setprio(0);
    __syncthreads();                         // vmcnt+lgkm drain once per K-tile
    cur ^= 1;
  }

  // epilogue: D layout col = lane&15, row = (lane>>4)*4 + j
  const int colb = n0 + wc + lr;
  const int rowb = m0 + wr + lg * 4;
#pragma unroll
  for (int ni = 0; ni < 4; ni++) {
    const int col = colb + ni * 16;
    const float bv = bias[col];
#pragma unroll
    for (int mi = 0; mi < 4; mi++) {
#pragma unroll
      for (int j = 0; j < 4; j++) {
        const int row = rowb + mi * 16 + j;
        const size_t idx = (size_t)row * N + col;
        float v = acc[mi][ni][j] + bv;
        if constexpr (EPI == 0) {
          ((unsigned short*)Cout)[idx] = f2bf(v);
        } else if constexpr (EPI == 1) {
          ((unsigned short*)Cout)[idx] = f2bf(gelu_f(v));
        } else {
          ((float*)Cout)[idx] = v + resid[idx];
        }
      }
    }
  }
}

// ---------------- causal flash attention, 32x32 MFMA, swapped QK^T -----------
// 2-wave blocks: one 32-row q-tile per block, wave = key-tile parity half.
// Grid (bh fast, q-tile slow) for per-CU load balance + per-XCD head locality.
// In-register softmax (q = lane&31), defer-max, exp2 logits (Q pre-scaled).
// K prefetched one tile ahead; V loads hoisted to loop top.
__global__ __launch_bounds__(128) void attn32_k(const unsigned short* __restrict__ qkv,
                                                const unsigned short* __restrict__ vT,
                                                unsigned short* __restrict__ y) {
  __shared__ float smem[2][64][33];
  __shared__ float msh[2][64], lsh[2][64];

  const int t = threadIdx.x, w = t >> 6, lane = t & 63;
  const int ql = lane & 31, hi = lane >> 5;
  const int bh = blockIdx.x, bb = bh >> 4, hh = bh & 15;
  const int qt = 63 - blockIdx.y;                    // heavy tiles first
  const int half = w;
  const int q0 = qt * 32;

  const unsigned short* qp = qkv + (size_t)(bb * S_LEN + q0 + ql) * 3072 + hh * HDIM + hi * 8;
  const bf16x8 qf0 = *(const bf16x8*)(qp);
  const bf16x8 qf1 = *(const bf16x8*)(qp + 16);
  const bf16x8 qf2 = *(const bf16x8*)(qp + 32);
  const bf16x8 qf3 = *(const bf16x8*)(qp + 48);

  const unsigned short* kbp = qkv + (size_t)(bb * S_LEN) * 3072 + 1024 + hh * HDIM + hi * 8;
  const unsigned short* vbp = vT + (size_t)(bh * HDIM + ql) * (size_t)S_LEN + hi * 8;

  f32x16 acc0 = {}, acc1 = {};
  float m = -1e30f, l = 0.f;

  const int start = half * 32;

  const unsigned short* kp0 = kbp + (size_t)(start + ql) * 3072;
  bf16x8 kc0 = *(const bf16x8*)(kp0);
  bf16x8 kc1 = *(const bf16x8*)(kp0 + 16);
  bf16x8 kc2 = *(const bf16x8*)(kp0 + 32);
  bf16x8 kc3 = *(const bf16x8*)(kp0 + 48);

  for (int t0 = start; t0 <= q0; t0 += 64) {
    const unsigned short* vp = vbp + t0;
    const bf16x8 vf0 = *(const bf16x8*)(vp);
    const bf16x8 vf1 = *(const bf16x8*)(vp + 32 * S_LEN);
    const bf16x8 vf2 = *(const bf16x8*)(vp + 16);
    const bf16x8 vf3 = *(const bf16x8*)(vp + 32 * S_LEN + 16);

    __builtin_amdgcn_s_setprio(1);
    f32x16 st = {};
    st = __builtin_amdgcn_mfma_f32_32x32x16_bf16(kc0, qf0, st, 0, 0, 0);
    st = __builtin_amdgcn_mfma_f32_32x32x16_bf16(kc1, qf1, st, 0, 0, 0);
    st = __builtin_amdgcn_mfma_f32_32x32x16_bf16(kc2, qf2, st, 0, 0, 0);
    st = __builtin_amdgcn_mfma_f32_32x32x16_bf16(kc3, qf3, st, 0, 0, 0);
    __builtin_amdgcn_s_setprio(0);

    const int t1 = (t0 + 64 <= q0) ? (t0 + 64) : t0;
    const unsigned short* kpn = kbp + (size_t)(t1 + ql) * 3072;
    const bf16x8 kn0 = *(const bf16x8*)(kpn);
    const bf16x8 kn1 = *(const bf16x8*)(kpn + 16);
    const bf16x8 kn2 = *(const bf16x8*)(kpn + 32);
    const bf16x8 kn3 = *(const bf16x8*)(kpn + 48);

    if (t0 == q0) {                         // diagonal tile: causal mask
#pragma unroll
      for (int r = 0; r < 16; r++) {
        const int key = (r & 3) + 8 * (r >> 2) + 4 * hi;
        if (key > ql) st[r] = -1e30f;
      }
    }
    float pm = st[0];
#pragma unroll
    for (int r = 1; r < 16; r++) pm = fmaxf(pm, st[r]);
    pm = fmaxf(pm, __shfl_xor(pm, 32));
    if (!__all(pm - m <= 8.f)) {            // defer-max (T13)
      const float mn = fmaxf(m, pm);
      const float rs = exp2f(m - mn);
      l *= rs;
#pragma unroll
      for (int r = 0; r < 16; r++) { acc0[r] *= rs; acc1[r] *= rs; }
      m = mn;
    }
    float sum = 0.f;
#pragma unroll
    for (int r = 0; r < 16; r++) { st[r] = exp2f(st[r] - m); sum += st[r]; }
    sum += __shfl_xor(sum, 32);
    l += sum;

    {   // P^T B-frag, keys 0..15 of tile
      const unsigned c0 = cvtpk(st[0], st[1]), c1 = cvtpk(st[2], st[3]);
      const unsigned c2 = cvtpk(st[4], st[5]), c3 = cvtpk(st[6], st[7]);
      const unsigned x0 = __shfl_xor(c0, 32), x1 = __shfl_xor(c1, 32);
      const unsigned x2 = __shfl_xor(c2, 32), x3 = __shfl_xor(c3, 32);
      u32x4 fu;
      fu.x = hi ? x2 : c0; fu.y = hi ? x3 : c1;
      fu.z = hi ? c2 : x0; fu.w = hi ? c3 : x1;
      const bf16x8 pf = __builtin_bit_cast(bf16x8, fu);
      __builtin_amdgcn_s_setprio(1);
      acc0 = __builtin_amdgcn_mfma_f32_32x32x16_bf16(vf0, pf, acc0, 0, 0, 0);
      acc1 = __builtin_amdgcn_mfma_f32_32x32x16_bf16(vf1, pf, acc1, 0, 0, 0);
      __builtin_amdgcn_s_setprio(0);
    }
    {   // keys 16..31
      const unsigned c4 = cvtpk(st[8], st[9]),   c5 = cvtpk(st[10], st[11]);
      const unsigned c6 = cvtpk(st[12], st[13]), c7 = cvtpk(st[14], st[15]);
      const unsigned x4 = __shfl_xor(c4, 32), x5 = __shfl_xor(c5, 32);
      const unsigned x6 = __shfl_xor(c6, 32), x7 = __shfl_xor(c7, 32);
      u32x4 fu;
      fu.x = hi ? x6 : c4; fu.y = hi ? x7 : c5;
      fu.z = hi ? c6 : x4; fu.w = hi ? c7 : x5;
      const bf16x8 pf = __builtin_bit_cast(bf16x8, fu);
      __builtin_amdgcn_s_setprio(1);
      acc0 = __builtin_amdgcn_mfma_f32_32x32x16_bf16(vf2, pf, acc0, 0, 0, 0);
      acc1 = __builtin_amdgcn_mfma_f32_32x32x16_bf16(vf3, pf, acc1, 0, 0, 0);
      __builtin_amdgcn_s_setprio(0);
    }
    kc0 = kn0; kc1 = kn1; kc2 = kn2; kc3 = kn3;   // rotate prefetched K
  }

  // ---- K-half merge via LDS ----
#pragma unroll
  for (int r = 0; r < 16; r++) {
    smem[w][lane][r]      = acc0[r];
    smem[w][lane][16 + r] = acc1[r];
  }
  msh[w][lane] = m; lsh[w][lane] = l;
  __syncthreads();
  if (half) return;

  const int pw = w ^ 1;
  const float mB = msh[pw][lane], lB = lsh[pw][lane];
  const float mm = fmaxf(m, mB);
  float sA = exp2f(m - mm), sB = exp2f(mB - mm);
  const float linv = 1.f / (l * sA + lB * sB);
  sA *= linv; sB *= linv;

  unsigned* tp = (unsigned*)&smem[w][0][0];       // reuse own slot: [32][34] u32
  const float* pa = &smem[pw][lane][0];
#pragma unroll
  for (int j = 0; j < 8; j++) {
    const int wd = (j & 1) + 4 * (j >> 1) + 2 * hi;
    const float a0 = acc0[2 * j] * sA + pa[2 * j] * sB;
    const float b0 = acc0[2 * j + 1] * sA + pa[2 * j + 1] * sB;
    tp[ql * 34 + wd] = cvtpk(a0, b0);
    const float a1 = acc1[2 * j] * sA + pa[16 + 2 * j] * sB;
    const float b1 = acc1[2 * j + 1] * sA + pa[16 + 2 * j + 1] * sB;
    tp[ql * 34 + 16 + wd] = cvtpk(a1, b1);
  }
  unsigned* yu = (unsigned*)y;
  const size_t yrow = (size_t)(bb * S_LEN + q0 + ql) * (DIM / 2) + hh * (HDIM / 2) + hi * 16;
#pragma unroll
  for (int i = 0; i < 8; i++) {
    const uint2 d2 = *(const uint2*)&tp[ql * 34 + hi * 16 + 2 * i];
    *(uint2*)&yu[yrow + 2 * i] = d2;
  }
}

// ---------------- LayerNorm (row = 1024), OUTBF: 1 -> bf16, 0 -> f32 ---------
template <int OUTBF>
__global__ __launch_bounds__(256) void ln_k(const float* __restrict__ X,
                                            const float* __restrict__ g,
                                            const float* __restrict__ be,
                                            void* __restrict__ out) {
  const int row = blockIdx.x, t = threadIdx.x;
  const float4 v = ((const float4*)(X + (size_t)row * DIM))[t];
  float s  = v.x + v.y + v.z + v.w;
  float s2 = v.x * v.x + v.y * v.y + v.z * v.z + v.w * v.w;
#pragma unroll
  for (int o = 32; o >= 1; o >>= 1) {
    s  += __shfl_down(s, o);
    s2 += __shfl_down(s2, o);
  }
  __shared__ float red[8];
  if ((t & 63) == 0) { red[t >> 6] = s; red[4 + (t >> 6)] = s2; }
  __syncthreads();
  s  = red[0] + red[1] + red[2] + red[3];
  s2 = red[4] + red[5] + red[6] + red[7];
  const float mu  = s * (1.0f / DIM);
  const float var = s2 * (1.0f / DIM) - mu * mu;
  const float r   = rsqrtf(var + 1e-5f);
  const float4 gv = ((const float4*)g)[t];
  const float4 bv = ((const float4*)be)[t];
  const float o0 = (v.x - mu) * r * gv.x + bv.x;
  const float o1 = (v.y - mu) * r * gv.y + bv.y;
  const float o2 = (v.z - mu) * r * gv.z + bv.z;
  const float o3 = (v.w - mu) * r * gv.w + bv.w;
  if constexpr (OUTBF) {
    ushort4 p; p.x = f2bf(o0); p.y = f2bf(o1); p.z = f2bf(o2); p.w = f2bf(o3);
    ((ushort4*)out)[(size_t)row * 256 + t] = p;
  } else {
    float4 p; p.x = o0; p.y = o1; p.z = o2; p.w = o3;
    ((float4*)out)[(size_t)row * 256 + t] = p;
  }
}

// ---------------------------------------------------------------------------
extern "C" void kernel_launch(void* const* d_in, const int* in_sizes, int n_in,
                              void* d_out, int out_size, void* d_ws, size_t ws_size,
                              hipStream_t stream) {
  const float* x   = (const float*)d_in[0];
  const float* Wq  = (const float*)d_in[1];
  const float* bq  = (const float*)d_in[2];
  const float* Wk  = (const float*)d_in[3];
  const float* bk  = (const float*)d_in[4];
  const float* Wv  = (const float*)d_in[5];
  const float* bv  = (const float*)d_in[6];
  const float* Wp  = (const float*)d_in[7];
  const float* bp  = (const float*)d_in[8];
  const float* g0  = (const float*)d_in[9];
  const float* be0 = (const float*)d_in[10];
  const float* W1  = (const float*)d_in[11];
  const float* b1  = (const float*)d_in[12];
  const float* W2  = (const float*)d_in[13];
  const float* b2  = (const float*)d_in[14];
  const float* g1  = (const float*)d_in[15];
  const float* be1 = (const float*)d_in[16];

  char* ws = (char*)d_ws;
  const size_t MB = 1ull << 20;
  unsigned short* xb    = (unsigned short*)(ws + 0 * MB);   //  8 MB
  unsigned short* qkvb  = (unsigned short*)(ws + 8 * MB);   // 24 MB [4096][3072]
  unsigned short* vTb   = (unsigned short*)(ws + 32 * MB);  //  8 MB
  unsigned short* yb    = (unsigned short*)(ws + 40 * MB);  //  8 MB
  float*          bqkv  = (float*)(ws + 48 * MB);           // 12 KB (dead before x1 write)
  float*          x1    = (float*)(ws + 48 * MB);           // 16 MB
  unsigned short* hb    = (unsigned short*)(ws + 64 * MB);  //  8 MB
  unsigned short* WqkvT = (unsigned short*)(ws + 72 * MB);  //  6 MB [3072][1024]
  unsigned short* WpT   = (unsigned short*)(ws + 78 * MB);  //  2 MB
  unsigned short* W1T   = (unsigned short*)(ws + 80 * MB);  //  8 MB
  unsigned short* W2T   = (unsigned short*)(ws + 88 * MB);  //  8 MB -> 96 MB
  unsigned short* h1    = (unsigned short*)(ws + 8 * MB);   // 32 MB alias qkvb+vTb (dead)
  float*          x2    = (float*)(ws + 64 * MB);           // 16 MB alias hb+WqkvT+WpT (dead)

  // 1) casts / transposes (Q weights+bias pre-scaled by 0.125*log2e)
  cast_f32_bf16<<<2048, 256, 0, stream>>>(x, xb);
  tcast_k<<<dim3(32, 32), 256, 0, stream>>>(Wq, WqkvT,               1024, 1024, QS);
  tcast_k<<<dim3(32, 32), 256, 0, stream>>>(Wk, WqkvT + 1024 * 1024, 1024, 1024, 1.f);
  tcast_k<<<dim3(32, 32), 256, 0, stream>>>(Wv, WqkvT + 2048 * 1024, 1024, 1024, 1.f);
  tcast_k<<<dim3(32, 32), 256, 0, stream>>>(Wp, WpT, 1024, 1024, 1.f);
  tcast_k<<<dim3(128, 32), 256, 0, stream>>>(W1, W1T, 1024, 4096, 1.f);
  tcast_k<<<dim3(32, 128), 256, 0, stream>>>(W2, W2T, 4096, 1024, 1.f);
  bcat_k<<<12, 256, 0, stream>>>(bq, bk, bv, bqkv);

  // 2) fused QKV projection: [4096][3072]
  gemm2p<0><<<dim3(24, 32), 256, 0, stream>>>(xb, WqkvT, bqkv, nullptr, qkvb, MTOK, 3072, 1024);

  // 3) attention (bh fast dim for per-CU qt balance + per-XCD head locality)
  vtrans_k<<<dim3(32, 32), 256, 0, stream>>>(qkvb, vTb);
  attn32_k<<<dim3(32, 64), 128, 0, stream>>>(qkvb, vTb, yb);

  // 4) out-proj + residual (fp32), LN1 -> bf16
  gemm2p<2><<<dim3(8, 32), 256, 0, stream>>>(yb, WpT, bp, x, x1, MTOK, DIM, DIM);
  ln_k<1><<<4096, 256, 0, stream>>>(x1, g0, be0, hb);

  // 5) MLP: gelu(h@W1+b1) -> h1 ; h1@W2+b2 + x1 -> x2 ; LN2 -> out (f32)
  gemm2p<1><<<dim3(32, 32), 256, 0, stream>>>(hb, W1T, b1, nullptr, h1, MTOK, DFF, DIM);
  gemm2p<2><<<dim3(8, 32), 256, 0, stream>>>(h1, W2T, b2, x1, x2, MTOK, DIM, DFF);
  ln_k<0><<<4096, 256, 0, stream>>>(x2, g1, be1, d_out);
}

// Round 8
// 461.018 us; speedup vs baseline: 1.4289x; 1.0024x over previous
//
#include <hip/hip_runtime.h>
#include <stdint.h>

// Problem dims (fixed)
#define S_LEN 2048
#define DIM   1024
#define NH    16
#define HDIM  64
#define MTOK  4096   // B*S
#define DFF   4096

#define QS 0.18033688011112042f   // 0.125 * log2(e): attn uses exp2

typedef short bf16x8 __attribute__((ext_vector_type(8)));
typedef float f32x4  __attribute__((ext_vector_type(4)));
typedef float f32x16 __attribute__((ext_vector_type(16)));
typedef unsigned int u32x4 __attribute__((ext_vector_type(4)));

__device__ __forceinline__ unsigned short f2bf(float f) {
  unsigned int u = __float_as_uint(f);
  u += 0x7fffu + ((u >> 16) & 1u);          // RNE
  return (unsigned short)(u >> 16);
}

__device__ __forceinline__ unsigned cvtpk(float a, float b) {
  unsigned r;
  asm("v_cvt_pk_bf16_f32 %0, %1, %2" : "=v"(r) : "v"(a), "v"(b));
  return r;
}

__device__ __forceinline__ float gelu_f(float x) {
  const float c = 0.7978845608028654f;       // sqrt(2/pi)
  float u = c * (x + 0.044715f * x * x * x);
  return 0.5f * x * (1.0f + tanhf(u));
}

__device__ __forceinline__ void gld_lds16(const void* g, void* lds) {
  using gu32p = __attribute__((address_space(1))) unsigned int*;
  using lu32p = __attribute__((address_space(3))) unsigned int*;
  __builtin_amdgcn_global_load_lds((gu32p)g, (lu32p)lds, 16, 0, 0);
}

// ---------------- cast fp32 -> bf16 (vectorized, 8 elems/thread) -------------
__global__ __launch_bounds__(256) void cast_f32_bf16(const float* __restrict__ x,
                                                     unsigned short* __restrict__ xb) {
  const size_t i = (size_t)blockIdx.x * 256 + threadIdx.x;
  const float4 a = ((const float4*)x)[2 * i];
  const float4 b = ((const float4*)x)[2 * i + 1];
  ushort4 p0, p1;
  p0.x = f2bf(a.x); p0.y = f2bf(a.y); p0.z = f2bf(a.z); p0.w = f2bf(a.w);
  p1.x = f2bf(b.x); p1.y = f2bf(b.y); p1.z = f2bf(b.z); p1.w = f2bf(b.w);
  ((ushort4*)xb)[2 * i]     = p0;
  ((ushort4*)xb)[2 * i + 1] = p1;
}

// ------------- transpose+cast+scale: W[K][N] f32 -> Wt[N][K] bf16 ------------
__global__ __launch_bounds__(256) void tcast_k(const float* __restrict__ W,
                                               unsigned short* __restrict__ Wt,
                                               int K, int N, float scale) {
  __shared__ float tile[32][33];
  const int tx = threadIdx.x & 31, ty = threadIdx.x >> 5;
  const int n0 = blockIdx.x * 32, k0 = blockIdx.y * 32;
#pragma unroll
  for (int i = 0; i < 4; i++)
    tile[ty + 8 * i][tx] = W[(size_t)(k0 + ty + 8 * i) * N + n0 + tx];
  __syncthreads();
#pragma unroll
  for (int i = 0; i < 4; i++)
    Wt[(size_t)(n0 + ty + 8 * i) * K + k0 + tx] = f2bf(tile[tx][ty + 8 * i] * scale);
}

// ------------- concat (+scale q) biases into bqkv[3072] ----------------------
__global__ __launch_bounds__(256) void bcat_k(const float* __restrict__ bq,
                                              const float* __restrict__ bk,
                                              const float* __restrict__ bv,
                                              float* __restrict__ bqkv) {
  const int t = blockIdx.x * 256 + threadIdx.x;
  float v;
  if (t < 1024)      v = bq[t] * QS;
  else if (t < 2048) v = bk[t - 1024];
  else               v = bv[t - 2048];
  bqkv[t] = v;
}

// ------------- out[row][c] = X[row][c] + b[c]   (split-K GEMM base) ----------
__global__ __launch_bounds__(256) void resinit_k(const float* __restrict__ X,
                                                 const float* __restrict__ b,
                                                 float* __restrict__ out) {
  const int row = blockIdx.x, t = threadIdx.x;
  const float4 xv = ((const float4*)(X + (size_t)row * DIM))[t];
  const float4 bv = ((const float4*)b)[t];
  float4 o;
  o.x = xv.x + bv.x; o.y = xv.y + bv.y; o.z = xv.z + bv.z; o.w = xv.w + bv.w;
  ((float4*)(out + (size_t)row * DIM))[t] = o;
}

// ------------- transpose V (inside qkv, stride 3072) -> vT[(b,h,d)][s] -------
__global__ __launch_bounds__(256) void vtrans_k(const unsigned short* __restrict__ qkv,
                                                unsigned short* __restrict__ vT) {
  __shared__ unsigned short tile[64][65];
  const int bh = blockIdx.y, b = bh >> 4, h = bh & 15;
  const int s0 = blockIdx.x * 64;
  const int t = threadIdx.x;
#pragma unroll
  for (int i = 0; i < 16; i++) {
    int idx = i * 256 + t, r = idx >> 6, c = idx & 63;
    tile[r][c] = qkv[(size_t)(b * S_LEN + s0 + r) * 3072 + 2048 + h * HDIM + c];
  }
  __syncthreads();
#pragma unroll
  for (int i = 0; i < 16; i++) {
    int idx = i * 256 + t, d = idx >> 6, s = idx & 63;
    vT[(size_t)(bh * HDIM + d) * S_LEN + s0 + s] = tile[s][d];
  }
}

// ------- 2-phase dbuf GEMM with counted vmcnt (T4): C = A[M,K]*Bt[N,K]^T -----
// Per K-tile: issue next tile's 8 global_load_lds -> s_waitcnt vmcnt(8)
// (waits only PREVIOUS tile's loads: they had a whole K-tile to land) ->
// s_barrier -> ds_read+MFMA -> s_barrier (protects buffer overwrite).
// No vmcnt(0) drain in the main loop. Split-K via gridDim.z (EPI=3:
// f32 unsafeAtomicAdd into a resinit'd output).
// EPI: 0 = bf16 out (+bias), 1 = bf16 gelu out (+bias), 3 = f32 atomicAdd
template <int EPI>
__global__ __launch_bounds__(256, 2) void gemm2p(const unsigned short* __restrict__ A,
                                                 const unsigned short* __restrict__ Bt,
                                                 const float* __restrict__ bias,
                                                 void* __restrict__ Cout,
                                                 int M, int N, int K) {
  __shared__ alignas(16) short As[2][128 * 64];
  __shared__ alignas(16) short Bs[2][128 * 64];
  const int t = threadIdx.x, w = t >> 6, lane = t & 63;

  const int gx = gridDim.x, nwg = gx * gridDim.y;
  const int bid = blockIdx.x + gx * blockIdx.y;
  const int swz = (bid & 7) * (nwg >> 3) + (bid >> 3);   // bijective (nwg%8==0)
  const int m0 = (swz / gx) * 128, n0 = (swz % gx) * 128;

  const int wr = (w >> 1) * 64, wc = (w & 1) * 64;
  const int lr = lane & 15, lg = lane >> 4;

  f32x4 acc[4][4] = {};

  // staging: wave w stages rows [w*32, w*32+32); lane's 16B:
  // row = w*32 + i*8 + (lane>>3), col-chunk = lane&7 (K-contig)
  const int sr = w * 32 + (lane >> 3);
  const int sc = (lane & 7) * 8;
  const unsigned short* Ag = A + (size_t)(m0 + sr) * K + sc;
  const unsigned short* Bg = Bt + (size_t)(n0 + sr) * K + sc;
  const int dbase = w * 4096 + lane * 16;   // byte offset within 16KB tile

  const int Ks = K / gridDim.z;             // split-K chunk
  const int kbase = blockIdx.z * Ks;
  const int NT = Ks >> 6;                   // BK = 64

  // prologue: stage tile 0 -> buf 0 (8 loads in flight)
#pragma unroll
  for (int i = 0; i < 4; i++) {
    gld_lds16(Ag + (size_t)(i * 8) * K + kbase, (char*)As[0] + dbase + i * 1024);
    gld_lds16(Bg + (size_t)(i * 8) * K + kbase, (char*)Bs[0] + dbase + i * 1024);
  }

  int cur = 0;
  for (int kt = 0; kt < NT; ++kt) {
    if (kt + 1 < NT) {                      // issue next-tile loads FIRST
      const int k1 = kbase + ((kt + 1) << 6);
#pragma unroll
      for (int i = 0; i < 4; i++) {
        gld_lds16(Ag + (size_t)(i * 8) * K + k1, (char*)As[cur ^ 1] + dbase + i * 1024);
        gld_lds16(Bg + (size_t)(i * 8) * K + k1, (char*)Bs[cur ^ 1] + dbase + i * 1024);
      }
      asm volatile("s_waitcnt vmcnt(8)" ::: "memory");   // prev tile landed
    } else {
      asm volatile("s_waitcnt vmcnt(0)" ::: "memory");   // final tile landed
    }
    __builtin_amdgcn_s_barrier();           // all waves' current tile ready

    bf16x8 af[2][4], bfr[2][4];
#pragma unroll
    for (int ks = 0; ks < 2; ks++)
#pragma unroll
      for (int i = 0; i < 4; i++) {
        af[ks][i]  = *reinterpret_cast<const bf16x8*>(&As[cur][(wr + i * 16 + lr) * 64 + ks * 32 + lg * 8]);
        bfr[ks][i] = *reinterpret_cast<const bf16x8*>(&Bs[cur][(wc + i * 16 + lr) * 64 + ks * 32 + lg * 8]);
      }
    __builtin_amdgcn_s_setprio(1);
#pragma unroll
    for (int ks = 0; ks < 2; ks++)
#pragma unroll
      for (int mi = 0; mi < 4; mi++)
#pragma unroll
        for (int ni = 0; ni < 4; ni++)
          acc[mi][ni] = __builtin_amdgcn_mfma_f32_16x16x32_bf16(af[ks][mi], bfr[ks][ni],
                                                                acc[mi][ni], 0, 0, 0);
    __builtin_amdgcn_s_setprio(0);
    __builtin_amdgcn_s_barrier();           // readers done before overwrite
    cur ^= 1;
  }

  // epilogue: D layout col = lane&15, row = (lane>>4)*4 + j
  const int colb = n0 + wc + lr;
  const int rowb = m0 + wr + lg * 4;
#pragma unroll
  for (int ni = 0; ni < 4; ni++) {
    const int col = colb + ni * 16;
    const float bv = (EPI == 3) ? 0.f : bias[col];
#pragma unroll
    for (int mi = 0; mi < 4; mi++) {
#pragma unroll
      for (int j = 0; j < 4; j++) {
        const int row = rowb + mi * 16 + j;
        const size_t idx = (size_t)row * N + col;
        float v = acc[mi][ni][j] + bv;
        if constexpr (EPI == 0) {
          ((unsigned short*)Cout)[idx] = f2bf(v);
        } else if constexpr (EPI == 1) {
          ((unsigned short*)Cout)[idx] = f2bf(gelu_f(v));
        } else {
          unsafeAtomicAdd((float*)Cout + idx, v);
        }
      }
    }
  }
}

// ---------------- causal flash attention, 32x32 MFMA, swapped QK^T -----------
// 2-wave blocks: one 32-row q-tile per block, wave = key-tile parity half.
// Grid (bh fast, q-tile slow) for per-CU load balance + per-XCD head locality.
// In-register softmax (q = lane&31), defer-max, exp2 logits (Q pre-scaled).
// K prefetched one tile ahead; V loads hoisted to loop top.
__global__ __launch_bounds__(128) void attn32_k(const unsigned short* __restrict__ qkv,
                                                const unsigned short* __restrict__ vT,
                                                unsigned short* __restrict__ y) {
  __shared__ float smem[2][64][33];
  __shared__ float msh[2][64], lsh[2][64];

  const int t = threadIdx.x, w = t >> 6, lane = t & 63;
  const int ql = lane & 31, hi = lane >> 5;
  const int bh = blockIdx.x, bb = bh >> 4, hh = bh & 15;
  const int qt = 63 - blockIdx.y;                    // heavy tiles first
  const int half = w;
  const int q0 = qt * 32;

  const unsigned short* qp = qkv + (size_t)(bb * S_LEN + q0 + ql) * 3072 + hh * HDIM + hi * 8;
  const bf16x8 qf0 = *(const bf16x8*)(qp);
  const bf16x8 qf1 = *(const bf16x8*)(qp + 16);
  const bf16x8 qf2 = *(const bf16x8*)(qp + 32);
  const bf16x8 qf3 = *(const bf16x8*)(qp + 48);

  const unsigned short* kbp = qkv + (size_t)(bb * S_LEN) * 3072 + 1024 + hh * HDIM + hi * 8;
  const unsigned short* vbp = vT + (size_t)(bh * HDIM + ql) * (size_t)S_LEN + hi * 8;

  f32x16 acc0 = {}, acc1 = {};
  float m = -1e30f, l = 0.f;

  const int start = half * 32;

  const unsigned short* kp0 = kbp + (size_t)(start + ql) * 3072;
  bf16x8 kc0 = *(const bf16x8*)(kp0);
  bf16x8 kc1 = *(const bf16x8*)(kp0 + 16);
  bf16x8 kc2 = *(const bf16x8*)(kp0 + 32);
  bf16x8 kc3 = *(const bf16x8*)(kp0 + 48);

  for (int t0 = start; t0 <= q0; t0 += 64) {
    const unsigned short* vp = vbp + t0;
    const bf16x8 vf0 = *(const bf16x8*)(vp);
    const bf16x8 vf1 = *(const bf16x8*)(vp + 32 * S_LEN);
    const bf16x8 vf2 = *(const bf16x8*)(vp + 16);
    const bf16x8 vf3 = *(const bf16x8*)(vp + 32 * S_LEN + 16);

    __builtin_amdgcn_s_setprio(1);
    f32x16 st = {};
    st = __builtin_amdgcn_mfma_f32_32x32x16_bf16(kc0, qf0, st, 0, 0, 0);
    st = __builtin_amdgcn_mfma_f32_32x32x16_bf16(kc1, qf1, st, 0, 0, 0);
    st = __builtin_amdgcn_mfma_f32_32x32x16_bf16(kc2, qf2, st, 0, 0, 0);
    st = __builtin_amdgcn_mfma_f32_32x32x16_bf16(kc3, qf3, st, 0, 0, 0);
    __builtin_amdgcn_s_setprio(0);

    const int t1 = (t0 + 64 <= q0) ? (t0 + 64) : t0;
    const unsigned short* kpn = kbp + (size_t)(t1 + ql) * 3072;
    const bf16x8 kn0 = *(const bf16x8*)(kpn);
    const bf16x8 kn1 = *(const bf16x8*)(kpn + 16);
    const bf16x8 kn2 = *(const bf16x8*)(kpn + 32);
    const bf16x8 kn3 = *(const bf16x8*)(kpn + 48);

    if (t0 == q0) {                         // diagonal tile: causal mask
#pragma unroll
      for (int r = 0; r < 16; r++) {
        const int key = (r & 3) + 8 * (r >> 2) + 4 * hi;
        if (key > ql) st[r] = -1e30f;
      }
    }
    float pm = st[0];
#pragma unroll
    for (int r = 1; r < 16; r++) pm = fmaxf(pm, st[r]);
    pm = fmaxf(pm, __shfl_xor(pm, 32));
    if (!__all(pm - m <= 8.f)) {            // defer-max (T13)
      const float mn = fmaxf(m, pm);
      const float rs = exp2f(m - mn);
      l *= rs;
#pragma unroll
      for (int r = 0; r < 16; r++) { acc0[r] *= rs; acc1[r] *= rs; }
      m = mn;
    }
    float sum = 0.f;
#pragma unroll
    for (int r = 0; r < 16; r++) { st[r] = exp2f(st[r] - m); sum += st[r]; }
    sum += __shfl_xor(sum, 32);
    l += sum;

    {   // P^T B-frag, keys 0..15 of tile
      const unsigned c0 = cvtpk(st[0], st[1]), c1 = cvtpk(st[2], st[3]);
      const unsigned c2 = cvtpk(st[4], st[5]), c3 = cvtpk(st[6], st[7]);
      const unsigned x0 = __shfl_xor(c0, 32), x1 = __shfl_xor(c1, 32);
      const unsigned x2 = __shfl_xor(c2, 32), x3 = __shfl_xor(c3, 32);
      u32x4 fu;
      fu.x = hi ? x2 : c0; fu.y = hi ? x3 : c1;
      fu.z = hi ? c2 : x0; fu.w = hi ? c3 : x1;
      const bf16x8 pf = __builtin_bit_cast(bf16x8, fu);
      __builtin_amdgcn_s_setprio(1);
      acc0 = __builtin_amdgcn_mfma_f32_32x32x16_bf16(vf0, pf, acc0, 0, 0, 0);
      acc1 = __builtin_amdgcn_mfma_f32_32x32x16_bf16(vf1, pf, acc1, 0, 0, 0);
      __builtin_amdgcn_s_setprio(0);
    }
    {   // keys 16..31
      const unsigned c4 = cvtpk(st[8], st[9]),   c5 = cvtpk(st[10], st[11]);
      const unsigned c6 = cvtpk(st[12], st[13]), c7 = cvtpk(st[14], st[15]);
      const unsigned x4 = __shfl_xor(c4, 32), x5 = __shfl_xor(c5, 32);
      const unsigned x6 = __shfl_xor(c6, 32), x7 = __shfl_xor(c7, 32);
      u32x4 fu;
      fu.x = hi ? x6 : c4; fu.y = hi ? x7 : c5;
      fu.z = hi ? c6 : x4; fu.w = hi ? c7 : x5;
      const bf16x8 pf = __builtin_bit_cast(bf16x8, fu);
      __builtin_amdgcn_s_setprio(1);
      acc0 = __builtin_amdgcn_mfma_f32_32x32x16_bf16(vf2, pf, acc0, 0, 0, 0);
      acc1 = __builtin_amdgcn_mfma_f32_32x32x16_bf16(vf3, pf, acc1, 0, 0, 0);
      __builtin_amdgcn_s_setprio(0);
    }
    kc0 = kn0; kc1 = kn1; kc2 = kn2; kc3 = kn3;   // rotate prefetched K
  }

  // ---- K-half merge via LDS ----
#pragma unroll
  for (int r = 0; r < 16; r++) {
    smem[w][lane][r]      = acc0[r];
    smem[w][lane][16 + r] = acc1[r];
  }
  msh[w][lane] = m; lsh[w][lane] = l;
  __syncthreads();
  if (half) return;

  const int pw = w ^ 1;
  const float mB = msh[pw][lane], lB = lsh[pw][lane];
  const float mm = fmaxf(m, mB);
  float sA = exp2f(m - mm), sB = exp2f(mB - mm);
  const float linv = 1.f / (l * sA + lB * sB);
  sA *= linv; sB *= linv;

  unsigned* tp = (unsigned*)&smem[w][0][0];       // reuse own slot: [32][34] u32
  const float* pa = &smem[pw][lane][0];
#pragma unroll
  for (int j = 0; j < 8; j++) {
    const int wd = (j & 1) + 4 * (j >> 1) + 2 * hi;
    const float a0 = acc0[2 * j] * sA + pa[2 * j] * sB;
    const float b0 = acc0[2 * j + 1] * sA + pa[2 * j + 1] * sB;
    tp[ql * 34 + wd] = cvtpk(a0, b0);
    const float a1 = acc1[2 * j] * sA + pa[16 + 2 * j] * sB;
    const float b1 = acc1[2 * j + 1] * sA + pa[16 + 2 * j + 1] * sB;
    tp[ql * 34 + 16 + wd] = cvtpk(a1, b1);
  }
  unsigned* yu = (unsigned*)y;
  const size_t yrow = (size_t)(bb * S_LEN + q0 + ql) * (DIM / 2) + hh * (HDIM / 2) + hi * 16;
#pragma unroll
  for (int i = 0; i < 8; i++) {
    const uint2 d2 = *(const uint2*)&tp[ql * 34 + hi * 16 + 2 * i];
    *(uint2*)&yu[yrow + 2 * i] = d2;
  }
}

// ---------------- LayerNorm (row = 1024), OUTBF: 1 -> bf16, 0 -> f32 ---------
template <int OUTBF>
__global__ __launch_bounds__(256) void ln_k(const float* __restrict__ X,
                                            const float* __restrict__ g,
                                            const float* __restrict__ be,
                                            void* __restrict__ out) {
  const int row = blockIdx.x, t = threadIdx.x;
  const float4 v = ((const float4*)(X + (size_t)row * DIM))[t];
  float s  = v.x + v.y + v.z + v.w;
  float s2 = v.x * v.x + v.y * v.y + v.z * v.z + v.w * v.w;
#pragma unroll
  for (int o = 32; o >= 1; o >>= 1) {
    s  += __shfl_down(s, o);
    s2 += __shfl_down(s2, o);
  }
  __shared__ float red[8];
  if ((t & 63) == 0) { red[t >> 6] = s; red[4 + (t >> 6)] = s2; }
  __syncthreads();
  s  = red[0] + red[1] + red[2] + red[3];
  s2 = red[4] + red[5] + red[6] + red[7];
  const float mu  = s * (1.0f / DIM);
  const float var = s2 * (1.0f / DIM) - mu * mu;
  const float r   = rsqrtf(var + 1e-5f);
  const float4 gv = ((const float4*)g)[t];
  const float4 bv = ((const float4*)be)[t];
  const float o0 = (v.x - mu) * r * gv.x + bv.x;
  const float o1 = (v.y - mu) * r * gv.y + bv.y;
  const float o2 = (v.z - mu) * r * gv.z + bv.z;
  const float o3 = (v.w - mu) * r * gv.w + bv.w;
  if constexpr (OUTBF) {
    ushort4 p; p.x = f2bf(o0); p.y = f2bf(o1); p.z = f2bf(o2); p.w = f2bf(o3);
    ((ushort4*)out)[(size_t)row * 256 + t] = p;
  } else {
    float4 p; p.x = o0; p.y = o1; p.z = o2; p.w = o3;
    ((float4*)out)[(size_t)row * 256 + t] = p;
  }
}

// ---------------------------------------------------------------------------
extern "C" void kernel_launch(void* const* d_in, const int* in_sizes, int n_in,
                              void* d_out, int out_size, void* d_ws, size_t ws_size,
                              hipStream_t stream) {
  const float* x   = (const float*)d_in[0];
  const float* Wq  = (const float*)d_in[1];
  const float* bq  = (const float*)d_in[2];
  const float* Wk  = (const float*)d_in[3];
  const float* bk  = (const float*)d_in[4];
  const float* Wv  = (const float*)d_in[5];
  const float* bv  = (const float*)d_in[6];
  const float* Wp  = (const float*)d_in[7];
  const float* bp  = (const float*)d_in[8];
  const float* g0  = (const float*)d_in[9];
  const float* be0 = (const float*)d_in[10];
  const float* W1  = (const float*)d_in[11];
  const float* b1  = (const float*)d_in[12];
  const float* W2  = (const float*)d_in[13];
  const float* b2  = (const float*)d_in[14];
  const float* g1  = (const float*)d_in[15];
  const float* be1 = (const float*)d_in[16];

  char* ws = (char*)d_ws;
  const size_t MB = 1ull << 20;
  unsigned short* xb    = (unsigned short*)(ws + 0 * MB);   //  8 MB
  unsigned short* qkvb  = (unsigned short*)(ws + 8 * MB);   // 24 MB [4096][3072]
  unsigned short* vTb   = (unsigned short*)(ws + 32 * MB);  //  8 MB
  unsigned short* yb    = (unsigned short*)(ws + 40 * MB);  //  8 MB
  float*          bqkv  = (float*)(ws + 48 * MB);           // 12 KB (dead before x1 write)
  float*          x1    = (float*)(ws + 48 * MB);           // 16 MB
  unsigned short* hb    = (unsigned short*)(ws + 64 * MB);  //  8 MB
  unsigned short* WqkvT = (unsigned short*)(ws + 72 * MB);  //  6 MB [3072][1024]
  unsigned short* WpT   = (unsigned short*)(ws + 78 * MB);  //  2 MB
  unsigned short* W1T   = (unsigned short*)(ws + 80 * MB);  //  8 MB
  unsigned short* W2T   = (unsigned short*)(ws + 88 * MB);  //  8 MB -> 96 MB
  unsigned short* h1    = (unsigned short*)(ws + 8 * MB);   // 32 MB alias qkvb+vTb (dead)
  float*          x2    = (float*)(ws + 64 * MB);           // 16 MB alias hb+WqkvT+WpT (dead)

  // 1) casts / transposes (Q weights+bias pre-scaled by 0.125*log2e)
  cast_f32_bf16<<<2048, 256, 0, stream>>>(x, xb);
  tcast_k<<<dim3(32, 32), 256, 0, stream>>>(Wq, WqkvT,               1024, 1024, QS);
  tcast_k<<<dim3(32, 32), 256, 0, stream>>>(Wk, WqkvT + 1024 * 1024, 1024, 1024, 1.f);
  tcast_k<<<dim3(32, 32), 256, 0, stream>>>(Wv, WqkvT + 2048 * 1024, 1024, 1024, 1.f);
  tcast_k<<<dim3(32, 32), 256, 0, stream>>>(Wp, WpT, 1024, 1024, 1.f);
  tcast_k<<<dim3(128, 32), 256, 0, stream>>>(W1, W1T, 1024, 4096, 1.f);
  tcast_k<<<dim3(32, 128), 256, 0, stream>>>(W2, W2T, 4096, 1024, 1.f);
  bcat_k<<<12, 256, 0, stream>>>(bq, bk, bv, bqkv);

  // 2) fused QKV projection: [4096][3072]
  gemm2p<0><<<dim3(24, 32, 1), 256, 0, stream>>>(xb, WqkvT, bqkv, qkvb, MTOK, 3072, 1024);

  // 3) attention (bh fast dim for per-CU qt balance + per-XCD head locality)
  vtrans_k<<<dim3(32, 32), 256, 0, stream>>>(qkvb, vTb);
  attn32_k<<<dim3(32, 64), 128, 0, stream>>>(qkvb, vTb, yb);

  // 4) out-proj (split-K x2, atomic into x1 = x + bp), LN1 -> bf16
  resinit_k<<<4096, 256, 0, stream>>>(x, bp, x1);
  gemm2p<3><<<dim3(8, 32, 2), 256, 0, stream>>>(yb, WpT, nullptr, x1, MTOK, DIM, DIM);
  ln_k<1><<<4096, 256, 0, stream>>>(x1, g0, be0, hb);

  // 5) MLP: gelu(h@W1+b1) -> h1 ; W2 split-K x2 atomic into x2 = x1 + b2 ; LN2
  gemm2p<1><<<dim3(32, 32, 1), 256, 0, stream>>>(hb, W1T, b1, h1, MTOK, DFF, DIM);
  resinit_k<<<4096, 256, 0, stream>>>(x1, b2, x2);
  gemm2p<3><<<dim3(8, 32, 2), 256, 0, stream>>>(h1, W2T, nullptr, x2, MTOK, DIM, DFF);
  ln_k<0><<<4096, 256, 0, stream>>>(x2, g1, be1, d_out);
}